// Round 1
// baseline (622.301 us; speedup 1.0000x reference)
//
#include <hip/hip_runtime.h>
#include <math.h>

typedef float f4 __attribute__((ext_vector_type(4)));

#define BM 64
#define BN 64
#define BK 16

// scale[d] = rsqrt(var+eps)*gamma ; shift[d] = beta - mean*scale
__global__ __launch_bounds__(256) void prep_bn_kernel(
    const float* __restrict__ gamma, const float* __restrict__ beta,
    const float* __restrict__ mean, const float* __restrict__ var,
    float* __restrict__ scale, float* __restrict__ shift) {
  int d = blockIdx.x * blockDim.x + threadIdx.x;
  if (d < 512) {
    float s = rsqrtf(var[d] + 1e-3f) * gamma[d];
    scale[d] = s;
    shift[d] = beta[d] - mean[d] * s;
  }
}

// P[d][j] = coefs[j][d]^2 ; P[512+d][j] = -2*coefs[j][d]^2*centers[j][d]
// cvec[j] = sum_d coefs^2 * centers^2
__global__ __launch_bounds__(64) void prep_params_kernel(
    const float* __restrict__ coefs, const float* __restrict__ centers,
    float* __restrict__ P, float* __restrict__ cvec) {
  int j = blockIdx.x;
  int lane = threadIdx.x;
  float acc = 0.f;
  for (int d = lane; d < 512; d += 64) {
    float cf = coefs[j * 512 + d];
    float a = cf * cf;
    float ce = centers[j * 512 + d];
    P[(size_t)d * 512 + j] = a;
    P[(size_t)(512 + d) * 512 + j] = -2.f * a * ce;
    acc = fmaf(a * ce, ce, acc);
  }
#pragma unroll
  for (int off = 32; off; off >>= 1) acc += __shfl_xor(acc, off);
  if (lane == 0) cvec[j] = acc;
}

// NN fp32 GEMM, 64x64 tile, BK=16, 256 threads, 4x4 per thread.
// MODE 1: C=relu(acc+b1)            -> H[:,0:512]    (A = x, K=512)
// MODE 2: C=relu(1-(acc+cvec))      -> H[:,512:1024] (A = [xb^2|xb] on the fly from x, K=1024)
// MODE 3: emb=relu(acc+b_out); C = w0*x + w1*emb -> d_out (A = H, K=1024)
template <int MODE>
__global__ __launch_bounds__(256) void gemm_fused(
    const float* __restrict__ A, const float* __restrict__ Bmat,
    const float* __restrict__ bias, const float* __restrict__ scale,
    const float* __restrict__ shift, const float* __restrict__ xorig,
    const float* __restrict__ wadd, float* __restrict__ C, int K, int lda,
    int ldc, int coff) {
  __shared__ float As[BK][BM];
  __shared__ float Bs[BK][BN];
  const int tid = threadIdx.x;
  const int tx = tid & 15, ty = tid >> 4;
  const int m0 = blockIdx.y * BM, n0 = blockIdx.x * BN;
  const int sar = tid >> 2;        // A stage row (0..63)
  const int sac = (tid & 3) * 4;   // A stage col4
  const int sbr = tid >> 4;        // B stage row (0..15)
  const int sbc = (tid & 15) * 4;  // B stage col4
  float acc[4][4] = {};
  for (int k0 = 0; k0 < K; k0 += BK) {
    f4 av, bv;
    if (MODE == 2) {
      int kc = k0 + sac;
      int d0 = kc & 511;
      f4 xv = *(const f4*)(A + (size_t)(m0 + sar) * 512 + d0);
      f4 sc = *(const f4*)(scale + d0);
      f4 sh = *(const f4*)(shift + d0);
#pragma unroll
      for (int e = 0; e < 4; ++e) {
        float v = fmaf(xv[e], sc[e], sh[e]);
        av[e] = (kc < 512) ? v * v : v;
      }
    } else {
      av = *(const f4*)(A + (size_t)(m0 + sar) * lda + k0 + sac);
    }
    bv = *(const f4*)(Bmat + (size_t)(k0 + sbr) * 512 + n0 + sbc);
    __syncthreads();
#pragma unroll
    for (int e = 0; e < 4; ++e) As[sac + e][sar] = av[e];
    *(f4*)&Bs[sbr][sbc] = bv;
    __syncthreads();
#pragma unroll
    for (int kk = 0; kk < BK; ++kk) {
      f4 a = *(const f4*)&As[kk][ty * 4];
      f4 b = *(const f4*)&Bs[kk][tx * 4];
#pragma unroll
      for (int r = 0; r < 4; ++r)
#pragma unroll
        for (int c = 0; c < 4; ++c) acc[r][c] = fmaf(a[r], b[c], acc[r][c]);
    }
  }
  f4 bb = *(const f4*)(bias + n0 + tx * 4);
  float w0 = 0.f, w1 = 0.f;
  if (MODE == 3) {
    w0 = wadd[0];
    w1 = wadd[1];
  }
#pragma unroll
  for (int r = 0; r < 4; ++r) {
    int gm = m0 + ty * 4 + r;
    f4 outv;
    f4 xo;
    if (MODE == 3) xo = *(const f4*)(xorig + (size_t)gm * 512 + n0 + tx * 4);
#pragma unroll
    for (int c = 0; c < 4; ++c) {
      float v = acc[r][c] + bb[c];
      if (MODE == 1) v = fmaxf(v, 0.f);
      if (MODE == 2) v = fmaxf(1.f - v, 0.f);
      if (MODE == 3) v = fmaf(w1, fmaxf(v, 0.f), w0 * xo[c]);
      outv[c] = v;
    }
    *(f4*)(C + (size_t)gm * ldc + coff + n0 + tx * 4) = outv;
  }
}

// One wave per row of 512. Newton on f(tau)=sum(relu(z-tau))-1 (convex,
// piecewise linear): tau_{n+1} = (sum_{z>tau_n} z - 1)/k_n, monotone from
// tau0 = max(z)-1, exact at convergence. In-place: pre -> mask.
__global__ __launch_bounds__(256) void sparsemax_kernel(float* __restrict__ out) {
  int row = blockIdx.x * 4 + (threadIdx.x >> 6);
  int lane = threadIdx.x & 63;
  float* rp = out + (size_t)row * 512;
  f4 z0 = *(const f4*)(rp + lane * 8);
  f4 z1 = *(const f4*)(rp + lane * 8 + 4);
  float z[8];
#pragma unroll
  for (int e = 0; e < 4; ++e) {
    z[e] = z0[e];
    z[4 + e] = z1[e];
  }
  float m = z[0];
#pragma unroll
  for (int i = 1; i < 8; ++i) m = fmaxf(m, z[i]);
#pragma unroll
  for (int off = 32; off; off >>= 1) m = fmaxf(m, __shfl_xor(m, off));
  float tau = m - 1.0f;
  for (int it = 0; it < 32; ++it) {
    float s = 0.f, k = 0.f;
#pragma unroll
    for (int i = 0; i < 8; ++i) {
      if (z[i] > tau) {
        s += z[i] - tau;
        k += 1.f;
      }
    }
#pragma unroll
    for (int off = 32; off; off >>= 1) {
      s += __shfl_xor(s, off);
      k += __shfl_xor(k, off);
    }
    if (k < 0.5f) break;
    float tn = tau + (s - 1.f) / k;
    if (tn == tau) break;
    tau = tn;
  }
  // final exact tau from converged support
  float s = 0.f, k = 0.f;
#pragma unroll
  for (int i = 0; i < 8; ++i)
    if (z[i] > tau) {
      s += z[i];
      k += 1.f;
    }
#pragma unroll
  for (int off = 32; off; off >>= 1) {
    s += __shfl_xor(s, off);
    k += __shfl_xor(k, off);
  }
  float tauf = (k >= 0.5f) ? (s - 1.f) / k : (m - 1.f);
  f4 o0, o1;
#pragma unroll
  for (int e = 0; e < 4; ++e) {
    o0[e] = fmaxf(z[e] - tauf, 0.f);
    o1[e] = fmaxf(z[4 + e] - tauf, 0.f);
  }
  *(f4*)(rp + lane * 8) = o0;
  *(f4*)(rp + lane * 8 + 4) = o1;
}

extern "C" void kernel_launch(void* const* d_in, const int* in_sizes, int n_in,
                              void* d_out, int out_size, void* d_ws,
                              size_t ws_size, hipStream_t stream) {
  const float* x = (const float*)d_in[0];
  const float* W1 = (const float*)d_in[1];
  const float* b1 = (const float*)d_in[2];
  const float* centers = (const float*)d_in[3];
  const float* coefs = (const float*)d_in[4];
  const float* gamma = (const float*)d_in[5];
  const float* beta = (const float*)d_in[6];
  const float* mean = (const float*)d_in[7];
  const float* var = (const float*)d_in[8];
  const float* W_out = (const float*)d_in[9];
  const float* b_out = (const float*)d_in[10];
  const float* wadd = (const float*)d_in[11];
  float* out = (float*)d_out;

  char* ws = (char*)d_ws;
  float* H = (float*)ws;                               // 16384x1024 = 64 MB
  float* P = (float*)(ws + 67108864);                  // 1024x512   = 2 MB
  float* cvec = (float*)(ws + 67108864 + 2097152);     // 512
  float* scale = cvec + 512;                           // 512
  float* shift = scale + 512;                          // 512

  prep_bn_kernel<<<2, 256, 0, stream>>>(gamma, beta, mean, var, scale, shift);
  prep_params_kernel<<<512, 64, 0, stream>>>(coefs, centers, P, cvec);

  dim3 grid(512 / BN, 16384 / BM);
  gemm_fused<1><<<grid, 256, 0, stream>>>(x, W1, b1, nullptr, nullptr, nullptr,
                                          nullptr, H, 512, 512, 1024, 0);
  gemm_fused<2><<<grid, 256, 0, stream>>>(x, P, cvec, scale, shift, nullptr,
                                          nullptr, H, 1024, 512, 1024, 512);
  gemm_fused<3><<<grid, 256, 0, stream>>>(H, W_out, b_out, nullptr, nullptr, x,
                                          wadd, out, 1024, 1024, 512, 0);
  sparsemax_kernel<<<4096, 256, 0, stream>>>(out);
}

// Round 5
// 136.362 us; speedup vs baseline: 4.5636x; 4.5636x over previous
//
#include <hip/hip_runtime.h>
#include <math.h>

typedef float f4 __attribute__((ext_vector_type(4)));
typedef float f32x4 __attribute__((ext_vector_type(4)));
typedef __bf16 bf16x8 __attribute__((ext_vector_type(8)));
typedef unsigned short u16;
typedef u16 us8 __attribute__((ext_vector_type(8)));

__device__ __forceinline__ u16 f2bf(float f) {
  unsigned u = __builtin_bit_cast(unsigned, f);
  unsigned r = u + 0x7fffu + ((u >> 16) & 1u);
  return (u16)(r >> 16);
}
__device__ __forceinline__ float bf2f(u16 h) {
  unsigned u = ((unsigned)h) << 16;
  return __builtin_bit_cast(float, u);
}

// scale[d] = rsqrt(var+eps)*gamma ; shift[d] = beta - mean*scale
__global__ __launch_bounds__(256) void prep_bn_kernel(
    const float* __restrict__ gamma, const float* __restrict__ beta,
    const float* __restrict__ mean, const float* __restrict__ var,
    float* __restrict__ scale, float* __restrict__ shift) {
  int d = blockIdx.x * blockDim.x + threadIdx.x;
  if (d < 512) {
    float s = rsqrtf(var[d] + 1e-3f) * gamma[d];
    scale[d] = s;
    shift[d] = beta[d] - mean[d] * s;
  }
}

// Pth[j][k] (bf16, [512][1024]): k<512 -> coefs^2 ; k>=512 -> -2*coefs^2*centers
// cvec[j] = sum_d coefs^2*centers^2  (fp32)
__global__ __launch_bounds__(64) void prep_params_kernel(
    const float* __restrict__ coefs, const float* __restrict__ centers,
    u16* __restrict__ pth, float* __restrict__ cvec) {
  int j = blockIdx.x;
  int l = threadIdx.x;
  int d0 = l * 8;
  f4 c0 = *(const f4*)(coefs + (size_t)j * 512 + d0);
  f4 c1 = *(const f4*)(coefs + (size_t)j * 512 + d0 + 4);
  f4 e0 = *(const f4*)(centers + (size_t)j * 512 + d0);
  f4 e1 = *(const f4*)(centers + (size_t)j * 512 + d0 + 4);
  us8 pa, pb;
  float acc = 0.f;
#pragma unroll
  for (int e = 0; e < 8; ++e) {
    float cf = (e < 4) ? c0[e] : c1[e - 4];
    float ce = (e < 4) ? e0[e] : e1[e - 4];
    float a = cf * cf;
    pa[e] = f2bf(a);
    pb[e] = f2bf(-2.f * a * ce);
    acc = fmaf(a * ce, ce, acc);
  }
  *(us8*)(pth + (size_t)j * 1024 + d0) = pa;
  *(us8*)(pth + (size_t)j * 1024 + 512 + d0) = pb;
#pragma unroll
  for (int off = 32; off; off >>= 1) acc += __shfl_xor(acc, off);
  if (l == 0) cvec[j] = acc;
}

// Transpose [K][N] fp32 -> Th, Tl [N][K] bf16 (hi/lo split)
__global__ __launch_bounds__(256) void transpose_split_kernel(
    const float* __restrict__ in, u16* __restrict__ th, u16* __restrict__ tl,
    int K, int N) {
  __shared__ float t[32][33];
  int lx = threadIdx.x;  // 32
  int ly = threadIdx.y;  // 8
  int n0 = blockIdx.x * 32, k0 = blockIdx.y * 32;
#pragma unroll
  for (int i = 0; i < 4; ++i)
    t[ly + 8 * i][lx] = in[(size_t)(k0 + ly + 8 * i) * N + n0 + lx];
  __syncthreads();
#pragma unroll
  for (int i = 0; i < 4; ++i) {
    float v = t[lx][ly + 8 * i];
    u16 h = f2bf(v);
    u16 lo = f2bf(v - bf2f(h));
    th[(size_t)(n0 + ly + 8 * i) * K + k0 + lx] = h;
    tl[(size_t)(n0 + ly + 8 * i) * K + k0 + lx] = lo;
  }
}

// x [16384][512] fp32 -> Xh = bf16(x), Xb = bf16(x*scale+shift)
__global__ __launch_bounds__(256) void conv_x_kernel(
    const float* __restrict__ x, const float* __restrict__ scale,
    const float* __restrict__ shift, u16* __restrict__ xh,
    u16* __restrict__ xb) {
  int gid = blockIdx.x * 256 + threadIdx.x;
  int m = gid >> 6;
  int d0 = (gid & 63) * 8;
  f4 v0 = *(const f4*)(x + (size_t)m * 512 + d0);
  f4 v1 = *(const f4*)(x + (size_t)m * 512 + d0 + 4);
  f4 s0 = *(const f4*)(scale + d0);
  f4 s1 = *(const f4*)(scale + d0 + 4);
  f4 h0 = *(const f4*)(shift + d0);
  f4 h1 = *(const f4*)(shift + d0 + 4);
  us8 oh, ob;
#pragma unroll
  for (int e = 0; e < 8; ++e) {
    float xv = (e < 4) ? v0[e] : v1[e - 4];
    float sc = (e < 4) ? s0[e] : s1[e - 4];
    float sh = (e < 4) ? h0[e] : h1[e - 4];
    oh[e] = f2bf(xv);
    ob[e] = f2bf(fmaf(xv, sc, sh));
  }
  *(us8*)(xh + (size_t)m * 512 + d0) = oh;
  *(us8*)(xb + (size_t)m * 512 + d0) = ob;
}

// MFMA GEMM: C[M][N] = A[M][K] @ Bt[N][K]^T, 128x128 tile, BK=64, 4 waves.
// PASSES==2: B split (A.Bh + A.Bl). PASSES==1: hi only.
// MODE 1: Hout[:, coff+n] = bf16(relu(acc + bias))
// MODE 2: A built on the fly from Xb: k<512 -> xb^2, k>=512 -> xb.
//         Hout[:, coff+n] = bf16(relu(1 - (acc + bias)))
// MODE 3: out = w0*x + w1*relu(acc + bias)  (fp32)
template <int MODE, int PASSES>
__global__ __launch_bounds__(256, 2) void gemm_mfma(
    const u16* __restrict__ Ah, const u16* __restrict__ Bh,
    const u16* __restrict__ Bl, const float* __restrict__ bias,
    const float* __restrict__ xorig, const float* __restrict__ wadd,
    u16* __restrict__ Hout, float* __restrict__ outp, int K, int lda,
    int coff) {
  extern __shared__ char smem[];
  char* sA = smem;
  char* sBh = smem + 16384;
  char* sBl = smem + 32768;
  const int tid = threadIdx.x;
  const int l = tid & 63;
  const int w = tid >> 6;
  const int wm = w & 1, wn = w >> 1;
  const int lr = l & 15, lk = l >> 4;
  const int sx = lr & 7;
  const int m0 = blockIdx.y * 128, n0 = blockIdx.x * 128;
  const int srow = l >> 3;               // row within 8-row chunk
  const int sslot = (l & 7) ^ srow;      // pre-inverse-swizzled source slot

  f32x4 acc[4][4];
#pragma unroll
  for (int i = 0; i < 4; ++i)
#pragma unroll
    for (int j = 0; j < 4; ++j) acc[i][j] = (f32x4){0.f, 0.f, 0.f, 0.f};

  for (int k0 = 0; k0 < K; k0 += 64) {
#pragma unroll
    for (int p = 0; p < 4; ++p) {
      int c = p * 4 + w;
      int row = c * 8 + srow;
      int loff = c * 1024;
      size_t gob = (size_t)(n0 + row) * K + k0 + sslot * 8;
      __builtin_amdgcn_global_load_lds(
          (const __attribute__((address_space(1))) void*)(Bh + gob),
          (__attribute__((address_space(3))) void*)(sBh + loff), 16, 0, 0);
      if (PASSES == 2) {
        __builtin_amdgcn_global_load_lds(
            (const __attribute__((address_space(1))) void*)(Bl + gob),
            (__attribute__((address_space(3))) void*)(sBl + loff), 16, 0, 0);
      }
      if (MODE == 2) {
        int kb = (k0 < 512) ? k0 : (k0 - 512);
        us8 v = *(const us8*)(Ah + (size_t)(m0 + row) * 512 + kb + sslot * 8);
        us8 o;
        if (k0 < 512) {
#pragma unroll
          for (int e = 0; e < 8; ++e) {
            float f = bf2f(v[e]);
            o[e] = f2bf(f * f);
          }
        } else {
          o = v;
        }
        *(us8*)(sA + loff + l * 16) = o;  // write-side swizzle via sslot source
      } else {
        size_t goa = (size_t)(m0 + row) * lda + k0 + sslot * 8;
        __builtin_amdgcn_global_load_lds(
            (const __attribute__((address_space(1))) void*)(Ah + goa),
            (__attribute__((address_space(3))) void*)(sA + loff), 16, 0, 0);
      }
    }
    __syncthreads();
#pragma unroll
    for (int ks = 0; ks < 2; ++ks) {
      bf16x8 av[4], bv[4];
#pragma unroll
      for (int i = 0; i < 4; ++i)
        av[i] = *(const bf16x8*)(sA + (wm * 64 + i * 16 + lr) * 128 +
                                 (((ks * 4 + lk) ^ sx) * 16));
#pragma unroll
      for (int j = 0; j < 4; ++j)
        bv[j] = *(const bf16x8*)(sBh + (wn * 64 + j * 16 + lr) * 128 +
                                 (((ks * 4 + lk) ^ sx) * 16));
#pragma unroll
      for (int i = 0; i < 4; ++i)
#pragma unroll
        for (int j = 0; j < 4; ++j)
          acc[i][j] = __builtin_amdgcn_mfma_f32_16x16x32_bf16(av[i], bv[j],
                                                              acc[i][j], 0, 0, 0);
      if (PASSES == 2) {
#pragma unroll
        for (int j = 0; j < 4; ++j)
          bv[j] = *(const bf16x8*)(sBl + (wn * 64 + j * 16 + lr) * 128 +
                                   (((ks * 4 + lk) ^ sx) * 16));
#pragma unroll
        for (int i = 0; i < 4; ++i)
#pragma unroll
          for (int j = 0; j < 4; ++j)
            acc[i][j] = __builtin_amdgcn_mfma_f32_16x16x32_bf16(
                av[i], bv[j], acc[i][j], 0, 0, 0);
      }
    }
    __syncthreads();
  }

  const int mwb = m0 + wm * 64;
  const int nwb = n0 + wn * 64;
  if (MODE == 3) {
    float w0 = wadd[0], w1 = wadd[1];
#pragma unroll
    for (int j = 0; j < 4; ++j) {
      int n = nwb + j * 16 + lr;
      float bv = bias[n];
#pragma unroll
      for (int i = 0; i < 4; ++i) {
#pragma unroll
        for (int r = 0; r < 4; ++r) {
          int m = mwb + i * 16 + lk * 4 + r;
          float v = fmaxf(acc[i][j][r] + bv, 0.f);
          outp[(size_t)m * 512 + n] =
              fmaf(w1, v, w0 * xorig[(size_t)m * 512 + n]);
        }
      }
    }
  } else {
#pragma unroll
    for (int j = 0; j < 4; ++j) {
      int n = nwb + j * 16 + lr;
      float bv = bias[n];
#pragma unroll
      for (int i = 0; i < 4; ++i) {
#pragma unroll
        for (int r = 0; r < 4; ++r) {
          int m = mwb + i * 16 + lk * 4 + r;
          float v = acc[i][j][r] + bv;
          v = (MODE == 1) ? fmaxf(v, 0.f) : fmaxf(1.f - v, 0.f);
          Hout[(size_t)m * 1024 + coff + n] = f2bf(v);
        }
      }
    }
  }
}

// One wave per row of 512. Newton on f(tau)=sum(relu(z-tau))-1. In place.
__global__ __launch_bounds__(256) void sparsemax_kernel(float* __restrict__ out) {
  int row = blockIdx.x * 4 + (threadIdx.x >> 6);
  int lane = threadIdx.x & 63;
  float* rp = out + (size_t)row * 512;
  f4 z0 = *(const f4*)(rp + lane * 8);
  f4 z1 = *(const f4*)(rp + lane * 8 + 4);
  float z[8];
#pragma unroll
  for (int e = 0; e < 4; ++e) {
    z[e] = z0[e];
    z[4 + e] = z1[e];
  }
  float m = z[0];
#pragma unroll
  for (int i = 1; i < 8; ++i) m = fmaxf(m, z[i]);
#pragma unroll
  for (int off = 32; off; off >>= 1) m = fmaxf(m, __shfl_xor(m, off));
  float tau = m - 1.0f;
  for (int it = 0; it < 32; ++it) {
    float s = 0.f, k = 0.f;
#pragma unroll
    for (int i = 0; i < 8; ++i) {
      if (z[i] > tau) {
        s += z[i] - tau;
        k += 1.f;
      }
    }
#pragma unroll
    for (int off = 32; off; off >>= 1) {
      s += __shfl_xor(s, off);
      k += __shfl_xor(k, off);
    }
    if (k < 0.5f) break;
    float tn = tau + (s - 1.f) / k;
    if (tn == tau) break;
    tau = tn;
  }
  float s = 0.f, k = 0.f;
#pragma unroll
  for (int i = 0; i < 8; ++i)
    if (z[i] > tau) {
      s += z[i];
      k += 1.f;
    }
#pragma unroll
  for (int off = 32; off; off >>= 1) {
    s += __shfl_xor(s, off);
    k += __shfl_xor(k, off);
  }
  float tauf = (k >= 0.5f) ? (s - 1.f) / k : (m - 1.f);
  f4 o0, o1;
#pragma unroll
  for (int e = 0; e < 4; ++e) {
    o0[e] = fmaxf(z[e] - tauf, 0.f);
    o1[e] = fmaxf(z[4 + e] - tauf, 0.f);
  }
  *(f4*)(rp + lane * 8) = o0;
  *(f4*)(rp + lane * 8 + 4) = o1;
}

extern "C" void kernel_launch(void* const* d_in, const int* in_sizes, int n_in,
                              void* d_out, int out_size, void* d_ws,
                              size_t ws_size, hipStream_t stream) {
  const float* x = (const float*)d_in[0];
  const float* W1 = (const float*)d_in[1];
  const float* b1 = (const float*)d_in[2];
  const float* centers = (const float*)d_in[3];
  const float* coefs = (const float*)d_in[4];
  const float* gamma = (const float*)d_in[5];
  const float* beta = (const float*)d_in[6];
  const float* mean = (const float*)d_in[7];
  const float* var = (const float*)d_in[8];
  const float* W_out = (const float*)d_in[9];
  const float* b_out = (const float*)d_in[10];
  const float* wadd = (const float*)d_in[11];
  float* out = (float*)d_out;

  // Workspace layout: total 69,212,160 B == round-1-proven ws_size floor.
  char* ws = (char*)d_ws;
  u16* Hh = (u16*)(ws);                      // [16384][1024] bf16 = 32 MB
  u16* Xh = (u16*)(ws + 33554432);           // [16384][512]  bf16 = 16 MB
  u16* Xb = (u16*)(ws + 50331648);           // [16384][512]  bf16 = 16 MB
  // 2 MB pool at 64 MB, time-multiplexed:
  //   phase A (G1/G2): W1th@+0, W1tl@+0.5MB, Pth@+1MB
  //   phase B (G3):    Wth @+0,  Wtl @+1MB   (transposed after G2 in-stream)
  char* pool = ws + 67108864;
  u16* W1th = (u16*)(pool);
  u16* W1tl = (u16*)(pool + 524288);
  u16* Pth = (u16*)(pool + 1048576);
  u16* Wth = (u16*)(pool);
  u16* Wtl = (u16*)(pool + 1048576);
  float* cvec = (float*)(ws + 69206016);     // 2 KB
  float* scale = (float*)(ws + 69208064);    // 2 KB
  float* shift = (float*)(ws + 69210112);    // 2 KB

  prep_bn_kernel<<<2, 256, 0, stream>>>(gamma, beta, mean, var, scale, shift);
  prep_params_kernel<<<512, 64, 0, stream>>>(coefs, centers, Pth, cvec);
  transpose_split_kernel<<<dim3(16, 16), dim3(32, 8), 0, stream>>>(W1, W1th,
                                                                   W1tl, 512,
                                                                   512);
  conv_x_kernel<<<4096, 256, 0, stream>>>(x, scale, shift, Xh, Xb);

  dim3 grid(4, 128);
  gemm_mfma<1, 2><<<grid, 256, 49152, stream>>>(Xh, W1th, W1tl, b1, nullptr,
                                                nullptr, Hh, nullptr, 512, 512,
                                                0);
  gemm_mfma<2, 1><<<grid, 256, 32768, stream>>>(Xb, Pth, nullptr, cvec,
                                                nullptr, nullptr, Hh, nullptr,
                                                1024, 512, 512);
  // W_out transpose reuses the pool -> must run after G2 (stream-ordered).
  transpose_split_kernel<<<dim3(16, 32), dim3(32, 8), 0, stream>>>(W_out, Wth,
                                                                   Wtl, 1024,
                                                                   512);
  gemm_mfma<3, 2><<<grid, 256, 49152, stream>>>(Hh, Wth, Wtl, b_out, x, wadd,
                                                nullptr, out, 1024, 1024, 0);
  sparsemax_kernel<<<4096, 256, 0, stream>>>(out);
}

// Round 6
// 128.060 us; speedup vs baseline: 4.8595x; 1.0648x over previous
//
#include <hip/hip_runtime.h>
#include <math.h>

typedef float f4 __attribute__((ext_vector_type(4)));
typedef float f32x4 __attribute__((ext_vector_type(4)));
typedef __bf16 bf16x8 __attribute__((ext_vector_type(8)));
typedef unsigned short u16;
typedef u16 us8 __attribute__((ext_vector_type(8)));

__device__ __forceinline__ u16 f2bf(float f) {
  unsigned u = __builtin_bit_cast(unsigned, f);
  unsigned r = u + 0x7fffu + ((u >> 16) & 1u);
  return (u16)(r >> 16);
}
__device__ __forceinline__ float bf2f(u16 h) {
  unsigned u = ((unsigned)h) << 16;
  return __builtin_bit_cast(float, u);
}

// scale[d] = rsqrt(var+eps)*gamma ; shift[d] = beta - mean*scale
__global__ __launch_bounds__(256) void prep_bn_kernel(
    const float* __restrict__ gamma, const float* __restrict__ beta,
    const float* __restrict__ mean, const float* __restrict__ var,
    float* __restrict__ scale, float* __restrict__ shift) {
  int d = blockIdx.x * blockDim.x + threadIdx.x;
  if (d < 512) {
    float s = rsqrtf(var[d] + 1e-3f) * gamma[d];
    scale[d] = s;
    shift[d] = beta[d] - mean[d] * s;
  }
}

// Pth[j][k] (bf16, [512][1024]): k<512 -> coefs^2 ; k>=512 -> -2*coefs^2*centers
// cvec[j] = sum_d coefs^2*centers^2  (fp32)
__global__ __launch_bounds__(64) void prep_params_kernel(
    const float* __restrict__ coefs, const float* __restrict__ centers,
    u16* __restrict__ pth, float* __restrict__ cvec) {
  int j = blockIdx.x;
  int l = threadIdx.x;
  int d0 = l * 8;
  f4 c0 = *(const f4*)(coefs + (size_t)j * 512 + d0);
  f4 c1 = *(const f4*)(coefs + (size_t)j * 512 + d0 + 4);
  f4 e0 = *(const f4*)(centers + (size_t)j * 512 + d0);
  f4 e1 = *(const f4*)(centers + (size_t)j * 512 + d0 + 4);
  us8 pa, pb;
  float acc = 0.f;
#pragma unroll
  for (int e = 0; e < 8; ++e) {
    float cf = (e < 4) ? c0[e] : c1[e - 4];
    float ce = (e < 4) ? e0[e] : e1[e - 4];
    float a = cf * cf;
    pa[e] = f2bf(a);
    pb[e] = f2bf(-2.f * a * ce);
    acc = fmaf(a * ce, ce, acc);
  }
  *(us8*)(pth + (size_t)j * 1024 + d0) = pa;
  *(us8*)(pth + (size_t)j * 1024 + 512 + d0) = pb;
#pragma unroll
  for (int off = 32; off; off >>= 1) acc += __shfl_xor(acc, off);
  if (l == 0) cvec[j] = acc;
}

// Transpose [K][N] fp32 -> Th, Tl [N][K] bf16 (hi/lo split)
__global__ __launch_bounds__(256) void transpose_split_kernel(
    const float* __restrict__ in, u16* __restrict__ th, u16* __restrict__ tl,
    int K, int N) {
  __shared__ float t[32][33];
  int lx = threadIdx.x;  // 32
  int ly = threadIdx.y;  // 8
  int n0 = blockIdx.x * 32, k0 = blockIdx.y * 32;
#pragma unroll
  for (int i = 0; i < 4; ++i)
    t[ly + 8 * i][lx] = in[(size_t)(k0 + ly + 8 * i) * N + n0 + lx];
  __syncthreads();
#pragma unroll
  for (int i = 0; i < 4; ++i) {
    float v = t[lx][ly + 8 * i];
    u16 h = f2bf(v);
    u16 lo = f2bf(v - bf2f(h));
    th[(size_t)(n0 + ly + 8 * i) * K + k0 + lx] = h;
    tl[(size_t)(n0 + ly + 8 * i) * K + k0 + lx] = lo;
  }
}

// x [16384][512] fp32 -> Xh = bf16(x), Xb = bf16(x*scale+shift)
__global__ __launch_bounds__(256) void conv_x_kernel(
    const float* __restrict__ x, const float* __restrict__ scale,
    const float* __restrict__ shift, u16* __restrict__ xh,
    u16* __restrict__ xb) {
  int gid = blockIdx.x * 256 + threadIdx.x;
  int m = gid >> 6;
  int d0 = (gid & 63) * 8;
  f4 v0 = *(const f4*)(x + (size_t)m * 512 + d0);
  f4 v1 = *(const f4*)(x + (size_t)m * 512 + d0 + 4);
  f4 s0 = *(const f4*)(scale + d0);
  f4 s1 = *(const f4*)(scale + d0 + 4);
  f4 h0 = *(const f4*)(shift + d0);
  f4 h1 = *(const f4*)(shift + d0 + 4);
  us8 oh, ob;
#pragma unroll
  for (int e = 0; e < 8; ++e) {
    float xv = (e < 4) ? v0[e] : v1[e - 4];
    float sc = (e < 4) ? s0[e] : s1[e - 4];
    float sh = (e < 4) ? h0[e] : h1[e - 4];
    oh[e] = f2bf(xv);
    ob[e] = f2bf(fmaf(xv, sc, sh));
  }
  *(us8*)(xh + (size_t)m * 512 + d0) = oh;
  *(us8*)(xb + (size_t)m * 512 + d0) = ob;
}

// MFMA GEMM: C[M][N] = A[M][K] @ Bt[N][K]^T, 128x128 tile, BK=64, 4 waves.
// 1-D grid of 512 blocks, bijective XCD swizzle (512 % 8 == 0): each XCD
// owns 16 consecutive m-blocks x all 4 n-blocks -> A-tile reads are L2-local.
// PASSES==2: B split (A.Bh + A.Bl). PASSES==1: hi only.
// MODE 1: Hout[:, coff+n] = bf16(relu(acc + bias))
// MODE 2: A built on the fly from Xb: k<512 -> xb^2, k>=512 -> xb.
//         Hout[:, coff+n] = bf16(relu(1 - (acc + bias)))
// MODE 3: out = w0*x + w1*relu(acc + bias)  (fp32)
template <int MODE, int PASSES>
__global__ __launch_bounds__(256, 2) void gemm_mfma(
    const u16* __restrict__ Ah, const u16* __restrict__ Bh,
    const u16* __restrict__ Bl, const float* __restrict__ bias,
    const float* __restrict__ xorig, const float* __restrict__ wadd,
    u16* __restrict__ Hout, float* __restrict__ outp, int K, int lda,
    int coff) {
  extern __shared__ char smem[];
  char* sA = smem;
  char* sBh = smem + 16384;
  char* sBl = smem + 32768;
  const int tid = threadIdx.x;
  const int l = tid & 63;
  const int w = tid >> 6;
  const int wm = w & 1, wn = w >> 1;
  const int lr = l & 15, lk = l >> 4;
  const int sx = lr & 7;
  // XCD swizzle: XCD (bid&7) gets contiguous chunk of 64 logical blocks.
  const int bid = blockIdx.x;
  const int lin = (bid & 7) * 64 + (bid >> 3);
  const int m0 = (lin >> 2) * 128, n0 = (lin & 3) * 128;
  const int srow = l >> 3;               // row within 8-row chunk
  const int sslot = (l & 7) ^ srow;      // pre-inverse-swizzled source slot

  f32x4 acc[4][4];
#pragma unroll
  for (int i = 0; i < 4; ++i)
#pragma unroll
    for (int j = 0; j < 4; ++j) acc[i][j] = (f32x4){0.f, 0.f, 0.f, 0.f};

  for (int k0 = 0; k0 < K; k0 += 64) {
#pragma unroll
    for (int p = 0; p < 4; ++p) {
      int c = p * 4 + w;
      int row = c * 8 + srow;
      int loff = c * 1024;
      size_t gob = (size_t)(n0 + row) * K + k0 + sslot * 8;
      __builtin_amdgcn_global_load_lds(
          (const __attribute__((address_space(1))) void*)(Bh + gob),
          (__attribute__((address_space(3))) void*)(sBh + loff), 16, 0, 0);
      if (PASSES == 2) {
        __builtin_amdgcn_global_load_lds(
            (const __attribute__((address_space(1))) void*)(Bl + gob),
            (__attribute__((address_space(3))) void*)(sBl + loff), 16, 0, 0);
      }
      if (MODE == 2) {
        int kb = (k0 < 512) ? k0 : (k0 - 512);
        us8 v = *(const us8*)(Ah + (size_t)(m0 + row) * 512 + kb + sslot * 8);
        us8 o;
        if (k0 < 512) {
#pragma unroll
          for (int e = 0; e < 8; ++e) {
            float f = bf2f(v[e]);
            o[e] = f2bf(f * f);
          }
        } else {
          o = v;
        }
        *(us8*)(sA + loff + l * 16) = o;  // write-side swizzle via sslot source
      } else {
        size_t goa = (size_t)(m0 + row) * lda + k0 + sslot * 8;
        __builtin_amdgcn_global_load_lds(
            (const __attribute__((address_space(1))) void*)(Ah + goa),
            (__attribute__((address_space(3))) void*)(sA + loff), 16, 0, 0);
      }
    }
    __syncthreads();
#pragma unroll
    for (int ks = 0; ks < 2; ++ks) {
      bf16x8 av[4], bv[4];
#pragma unroll
      for (int i = 0; i < 4; ++i)
        av[i] = *(const bf16x8*)(sA + (wm * 64 + i * 16 + lr) * 128 +
                                 (((ks * 4 + lk) ^ sx) * 16));
#pragma unroll
      for (int j = 0; j < 4; ++j)
        bv[j] = *(const bf16x8*)(sBh + (wn * 64 + j * 16 + lr) * 128 +
                                 (((ks * 4 + lk) ^ sx) * 16));
#pragma unroll
      for (int i = 0; i < 4; ++i)
#pragma unroll
        for (int j = 0; j < 4; ++j)
          acc[i][j] = __builtin_amdgcn_mfma_f32_16x16x32_bf16(av[i], bv[j],
                                                              acc[i][j], 0, 0, 0);
      if (PASSES == 2) {
#pragma unroll
        for (int j = 0; j < 4; ++j)
          bv[j] = *(const bf16x8*)(sBl + (wn * 64 + j * 16 + lr) * 128 +
                                   (((ks * 4 + lk) ^ sx) * 16));
#pragma unroll
        for (int i = 0; i < 4; ++i)
#pragma unroll
          for (int j = 0; j < 4; ++j)
            acc[i][j] = __builtin_amdgcn_mfma_f32_16x16x32_bf16(
                av[i], bv[j], acc[i][j], 0, 0, 0);
      }
    }
    __syncthreads();
  }

  const int mwb = m0 + wm * 64;
  const int nwb = n0 + wn * 64;
  if (MODE == 3) {
    float w0 = wadd[0], w1 = wadd[1];
#pragma unroll
    for (int j = 0; j < 4; ++j) {
      int n = nwb + j * 16 + lr;
      float bv = bias[n];
#pragma unroll
      for (int i = 0; i < 4; ++i) {
#pragma unroll
        for (int r = 0; r < 4; ++r) {
          int m = mwb + i * 16 + lk * 4 + r;
          float v = fmaxf(acc[i][j][r] + bv, 0.f);
          outp[(size_t)m * 512 + n] =
              fmaf(w1, v, w0 * xorig[(size_t)m * 512 + n]);
        }
      }
    }
  } else {
#pragma unroll
    for (int j = 0; j < 4; ++j) {
      int n = nwb + j * 16 + lr;
      float bv = bias[n];
#pragma unroll
      for (int i = 0; i < 4; ++i) {
#pragma unroll
        for (int r = 0; r < 4; ++r) {
          int m = mwb + i * 16 + lk * 4 + r;
          float v = acc[i][j][r] + bv;
          v = (MODE == 1) ? fmaxf(v, 0.f) : fmaxf(1.f - v, 0.f);
          Hout[(size_t)m * 1024 + coff + n] = f2bf(v);
        }
      }
    }
  }
}

// One wave per row of 512. Newton on f(tau)=sum(relu(z-tau))-1. In place.
__global__ __launch_bounds__(256) void sparsemax_kernel(float* __restrict__ out) {
  int row = blockIdx.x * 4 + (threadIdx.x >> 6);
  int lane = threadIdx.x & 63;
  float* rp = out + (size_t)row * 512;
  f4 z0 = *(const f4*)(rp + lane * 8);
  f4 z1 = *(const f4*)(rp + lane * 8 + 4);
  float z[8];
#pragma unroll
  for (int e = 0; e < 4; ++e) {
    z[e] = z0[e];
    z[4 + e] = z1[e];
  }
  float m = z[0];
#pragma unroll
  for (int i = 1; i < 8; ++i) m = fmaxf(m, z[i]);
#pragma unroll
  for (int off = 32; off; off >>= 1) m = fmaxf(m, __shfl_xor(m, off));
  float tau = m - 1.0f;
  for (int it = 0; it < 32; ++it) {
    float s = 0.f, k = 0.f;
#pragma unroll
    for (int i = 0; i < 8; ++i) {
      if (z[i] > tau) {
        s += z[i] - tau;
        k += 1.f;
      }
    }
#pragma unroll
    for (int off = 32; off; off >>= 1) {
      s += __shfl_xor(s, off);
      k += __shfl_xor(k, off);
    }
    if (k < 0.5f) break;
    float tn = tau + (s - 1.f) / k;
    if (tn == tau) break;
    tau = tn;
  }
  float s = 0.f, k = 0.f;
#pragma unroll
  for (int i = 0; i < 8; ++i)
    if (z[i] > tau) {
      s += z[i];
      k += 1.f;
    }
#pragma unroll
  for (int off = 32; off; off >>= 1) {
    s += __shfl_xor(s, off);
    k += __shfl_xor(k, off);
  }
  float tauf = (k >= 0.5f) ? (s - 1.f) / k : (m - 1.f);
  f4 o0, o1;
#pragma unroll
  for (int e = 0; e < 4; ++e) {
    o0[e] = fmaxf(z[e] - tauf, 0.f);
    o1[e] = fmaxf(z[4 + e] - tauf, 0.f);
  }
  *(f4*)(rp + lane * 8) = o0;
  *(f4*)(rp + lane * 8 + 4) = o1;
}

extern "C" void kernel_launch(void* const* d_in, const int* in_sizes, int n_in,
                              void* d_out, int out_size, void* d_ws,
                              size_t ws_size, hipStream_t stream) {
  const float* x = (const float*)d_in[0];
  const float* W1 = (const float*)d_in[1];
  const float* b1 = (const float*)d_in[2];
  const float* centers = (const float*)d_in[3];
  const float* coefs = (const float*)d_in[4];
  const float* gamma = (const float*)d_in[5];
  const float* beta = (const float*)d_in[6];
  const float* mean = (const float*)d_in[7];
  const float* var = (const float*)d_in[8];
  const float* W_out = (const float*)d_in[9];
  const float* b_out = (const float*)d_in[10];
  const float* wadd = (const float*)d_in[11];
  float* out = (float*)d_out;

  // Workspace layout: total 69,212,160 B == round-1-proven ws_size floor.
  char* ws = (char*)d_ws;
  u16* Hh = (u16*)(ws);                      // [16384][1024] bf16 = 32 MB
  u16* Xh = (u16*)(ws + 33554432);           // [16384][512]  bf16 = 16 MB
  u16* Xb = (u16*)(ws + 50331648);           // [16384][512]  bf16 = 16 MB
  // 2 MB pool at 64 MB, time-multiplexed:
  //   phase A (G1/G2): W1th@+0, W1tl@+0.5MB, Pth@+1MB
  //   phase B (G3):    Wth @+0,  Wtl @+1MB   (transposed after G2 in-stream)
  char* pool = ws + 67108864;
  u16* W1th = (u16*)(pool);
  u16* W1tl = (u16*)(pool + 524288);
  u16* Pth = (u16*)(pool + 1048576);
  u16* Wth = (u16*)(pool);
  u16* Wtl = (u16*)(pool + 1048576);
  float* cvec = (float*)(ws + 69206016);     // 2 KB
  float* scale = (float*)(ws + 69208064);    // 2 KB
  float* shift = (float*)(ws + 69210112);    // 2 KB

  prep_bn_kernel<<<2, 256, 0, stream>>>(gamma, beta, mean, var, scale, shift);
  prep_params_kernel<<<512, 64, 0, stream>>>(coefs, centers, Pth, cvec);
  transpose_split_kernel<<<dim3(16, 16), dim3(32, 8), 0, stream>>>(W1, W1th,
                                                                   W1tl, 512,
                                                                   512);
  conv_x_kernel<<<4096, 256, 0, stream>>>(x, scale, shift, Xh, Xb);

  // G1: 1-pass (hi-only W1). Error budget: adds ~1.3e-3 to pre (see theory).
  gemm_mfma<1, 1><<<512, 256, 32768, stream>>>(Xh, W1th, nullptr, b1, nullptr,
                                               nullptr, Hh, nullptr, 512, 512,
                                               0);
  gemm_mfma<2, 1><<<512, 256, 32768, stream>>>(Xb, Pth, nullptr, cvec,
                                               nullptr, nullptr, Hh, nullptr,
                                               1024, 512, 512);
  // W_out transpose reuses the pool -> must run after G2 (stream-ordered).
  transpose_split_kernel<<<dim3(16, 32), dim3(32, 8), 0, stream>>>(W_out, Wth,
                                                                   Wtl, 1024,
                                                                   512);
  gemm_mfma<3, 2><<<512, 256, 49152, stream>>>(Hh, Wth, Wtl, b_out, x, wadd,
                                               nullptr, out, 1024, 1024, 0);
  sparsemax_kernel<<<4096, 256, 0, stream>>>(out);
}

// Round 7
// 122.319 us; speedup vs baseline: 5.0875x; 1.0469x over previous
//
#include <hip/hip_runtime.h>
#include <math.h>

typedef float f4 __attribute__((ext_vector_type(4)));
typedef float f32x4 __attribute__((ext_vector_type(4)));
typedef __bf16 bf16x8 __attribute__((ext_vector_type(8)));
typedef unsigned short u16;
typedef u16 us8 __attribute__((ext_vector_type(8)));

__device__ __forceinline__ u16 f2bf(float f) {
  unsigned u = __builtin_bit_cast(unsigned, f);
  unsigned r = u + 0x7fffu + ((u >> 16) & 1u);
  return (u16)(r >> 16);
}
__device__ __forceinline__ float bf2f(u16 h) {
  unsigned u = ((unsigned)h) << 16;
  return __builtin_bit_cast(float, u);
}

// scale[d] = rsqrt(var+eps)*gamma ; shift[d] = beta - mean*scale
__global__ __launch_bounds__(256) void prep_bn_kernel(
    const float* __restrict__ gamma, const float* __restrict__ beta,
    const float* __restrict__ mean, const float* __restrict__ var,
    float* __restrict__ scale, float* __restrict__ shift) {
  int d = blockIdx.x * blockDim.x + threadIdx.x;
  if (d < 512) {
    float s = rsqrtf(var[d] + 1e-3f) * gamma[d];
    scale[d] = s;
    shift[d] = beta[d] - mean[d] * s;
  }
}

// Pth[j][k] (bf16, [512][1024]): k<512 -> coefs^2 ; k>=512 -> -2*coefs^2*centers
// cvec[j] = sum_d coefs^2*centers^2  (fp32)
__global__ __launch_bounds__(64) void prep_params_kernel(
    const float* __restrict__ coefs, const float* __restrict__ centers,
    u16* __restrict__ pth, float* __restrict__ cvec) {
  int j = blockIdx.x;
  int l = threadIdx.x;
  int d0 = l * 8;
  f4 c0 = *(const f4*)(coefs + (size_t)j * 512 + d0);
  f4 c1 = *(const f4*)(coefs + (size_t)j * 512 + d0 + 4);
  f4 e0 = *(const f4*)(centers + (size_t)j * 512 + d0);
  f4 e1 = *(const f4*)(centers + (size_t)j * 512 + d0 + 4);
  us8 pa, pb;
  float acc = 0.f;
#pragma unroll
  for (int e = 0; e < 8; ++e) {
    float cf = (e < 4) ? c0[e] : c1[e - 4];
    float ce = (e < 4) ? e0[e] : e1[e - 4];
    float a = cf * cf;
    pa[e] = f2bf(a);
    pb[e] = f2bf(-2.f * a * ce);
    acc = fmaf(a * ce, ce, acc);
  }
  *(us8*)(pth + (size_t)j * 1024 + d0) = pa;
  *(us8*)(pth + (size_t)j * 1024 + 512 + d0) = pb;
#pragma unroll
  for (int off = 32; off; off >>= 1) acc += __shfl_xor(acc, off);
  if (l == 0) cvec[j] = acc;
}

// Transpose [K][N] fp32 -> Th, Tl [N][K] bf16 (hi/lo split)
__global__ __launch_bounds__(256) void transpose_split_kernel(
    const float* __restrict__ in, u16* __restrict__ th, u16* __restrict__ tl,
    int K, int N) {
  __shared__ float t[32][33];
  int lx = threadIdx.x;  // 32
  int ly = threadIdx.y;  // 8
  int n0 = blockIdx.x * 32, k0 = blockIdx.y * 32;
#pragma unroll
  for (int i = 0; i < 4; ++i)
    t[ly + 8 * i][lx] = in[(size_t)(k0 + ly + 8 * i) * N + n0 + lx];
  __syncthreads();
#pragma unroll
  for (int i = 0; i < 4; ++i) {
    float v = t[lx][ly + 8 * i];
    u16 h = f2bf(v);
    u16 lo = f2bf(v - bf2f(h));
    th[(size_t)(n0 + ly + 8 * i) * K + k0 + lx] = h;
    tl[(size_t)(n0 + ly + 8 * i) * K + k0 + lx] = lo;
  }
}

// x [16384][512] fp32 -> Xh = bf16(x), Xb = bf16(x*scale+shift)
__global__ __launch_bounds__(256) void conv_x_kernel(
    const float* __restrict__ x, const float* __restrict__ scale,
    const float* __restrict__ shift, u16* __restrict__ xh,
    u16* __restrict__ xb) {
  int gid = blockIdx.x * 256 + threadIdx.x;
  int m = gid >> 6;
  int d0 = (gid & 63) * 8;
  f4 v0 = *(const f4*)(x + (size_t)m * 512 + d0);
  f4 v1 = *(const f4*)(x + (size_t)m * 512 + d0 + 4);
  f4 s0 = *(const f4*)(scale + d0);
  f4 s1 = *(const f4*)(scale + d0 + 4);
  f4 h0 = *(const f4*)(shift + d0);
  f4 h1 = *(const f4*)(shift + d0 + 4);
  us8 oh, ob;
#pragma unroll
  for (int e = 0; e < 8; ++e) {
    float xv = (e < 4) ? v0[e] : v1[e - 4];
    float sc = (e < 4) ? s0[e] : s1[e - 4];
    float sh = (e < 4) ? h0[e] : h1[e - 4];
    oh[e] = f2bf(xv);
    ob[e] = f2bf(fmaf(xv, sc, sh));
  }
  *(us8*)(xh + (size_t)m * 512 + d0) = oh;
  *(us8*)(xb + (size_t)m * 512 + d0) = ob;
}

// Merged G1+G2: 1024 blocks, 128x128 tiles, BK=64, 1-pass each.
// Logical index L = p*8 + g*4 + n  (p = m-panel 0..127, g = gemm id, n = n-blk)
// XCD swizzle L = (bid&7)*128 + (bid>>3): each XCD owns 16 m-panels with BOTH
// gemms co-resident -> A panels are L2-local; 4 blocks/CU residency.
// g==0 (G1): A = Xh (gload_lds), B = W1th[512][512], Hout[:,n] = relu(acc+b1)
// g==1 (G2): A = on-the-fly from Xb (k<512 -> xb^2 else xb), B = Pth[512][1024],
//            Hout[:,512+n] = relu(1-(acc+cvec))
__global__ __launch_bounds__(256, 4) void gemm_fused12(
    const u16* __restrict__ Xh, const u16* __restrict__ Xb,
    const u16* __restrict__ W1th, const u16* __restrict__ Pth,
    const float* __restrict__ b1, const float* __restrict__ cvec,
    u16* __restrict__ Hout) {
  extern __shared__ char smem[];
  char* sA = smem;
  char* sBh = smem + 16384;
  const int tid = threadIdx.x;
  const int l = tid & 63;
  const int w = tid >> 6;
  const int wm = w & 1, wn = w >> 1;
  const int lr = l & 15, lk = l >> 4;
  const int sx = lr & 7;
  const int bid = blockIdx.x;
  const int L = (bid & 7) * 128 + (bid >> 3);
  const int p = L >> 3;
  const int g = (L >> 2) & 1;
  const int n = L & 3;
  const int m0 = p * 128, n0 = n * 128;
  const int Kg = g ? 1024 : 512;
  const u16* Bmat = g ? Pth : W1th;
  const u16* Amat = g ? Xb : Xh;
  const int srow = l >> 3;
  const int sslot = (l & 7) ^ srow;

  f32x4 acc[4][4];
#pragma unroll
  for (int i = 0; i < 4; ++i)
#pragma unroll
    for (int j = 0; j < 4; ++j) acc[i][j] = (f32x4){0.f, 0.f, 0.f, 0.f};

  for (int k0 = 0; k0 < Kg; k0 += 64) {
#pragma unroll
    for (int pp = 0; pp < 4; ++pp) {
      int c = pp * 4 + w;
      int row = c * 8 + srow;
      int loff = c * 1024;
      size_t gob = (size_t)(n0 + row) * Kg + k0 + sslot * 8;
      __builtin_amdgcn_global_load_lds(
          (const __attribute__((address_space(1))) void*)(Bmat + gob),
          (__attribute__((address_space(3))) void*)(sBh + loff), 16, 0, 0);
      if (g) {
        int kb = (k0 < 512) ? k0 : (k0 - 512);
        us8 v = *(const us8*)(Amat + (size_t)(m0 + row) * 512 + kb + sslot * 8);
        us8 o;
        if (k0 < 512) {
#pragma unroll
          for (int e = 0; e < 8; ++e) {
            float f = bf2f(v[e]);
            o[e] = f2bf(f * f);
          }
        } else {
          o = v;
        }
        *(us8*)(sA + loff + l * 16) = o;
      } else {
        size_t goa = (size_t)(m0 + row) * 512 + k0 + sslot * 8;
        __builtin_amdgcn_global_load_lds(
            (const __attribute__((address_space(1))) void*)(Amat + goa),
            (__attribute__((address_space(3))) void*)(sA + loff), 16, 0, 0);
      }
    }
    __syncthreads();
#pragma unroll
    for (int ks = 0; ks < 2; ++ks) {
      bf16x8 av[4], bv[4];
#pragma unroll
      for (int i = 0; i < 4; ++i)
        av[i] = *(const bf16x8*)(sA + (wm * 64 + i * 16 + lr) * 128 +
                                 (((ks * 4 + lk) ^ sx) * 16));
#pragma unroll
      for (int j = 0; j < 4; ++j)
        bv[j] = *(const bf16x8*)(sBh + (wn * 64 + j * 16 + lr) * 128 +
                                 (((ks * 4 + lk) ^ sx) * 16));
#pragma unroll
      for (int i = 0; i < 4; ++i)
#pragma unroll
        for (int j = 0; j < 4; ++j)
          acc[i][j] = __builtin_amdgcn_mfma_f32_16x16x32_bf16(av[i], bv[j],
                                                              acc[i][j], 0, 0, 0);
    }
    __syncthreads();
  }

  const int mwb = m0 + wm * 64;
  const int nwb = n0 + wn * 64;
  const float* bias = g ? cvec : b1;
#pragma unroll
  for (int j = 0; j < 4; ++j) {
    int nn = nwb + j * 16 + lr;
    float bv = bias[nn];
#pragma unroll
    for (int i = 0; i < 4; ++i) {
#pragma unroll
      for (int r = 0; r < 4; ++r) {
        int m = mwb + i * 16 + lk * 4 + r;
        float v = acc[i][j][r] + bv;
        v = g ? fmaxf(1.f - v, 0.f) : fmaxf(v, 0.f);
        Hout[(size_t)m * 1024 + g * 512 + nn] = f2bf(v);
      }
    }
  }
}

// G3: out = w0*x + w1*relu(Hh @ W_out^T + b_out). K=1024, 128x128, BK=64.
// Split-K precision: lo-pass (Bl) only for k<512 (h1 rows; h2 ~ 0 so the
// k>=512 lo-correction is negligible). 512 blocks, XCD swizzle as before.
__global__ __launch_bounds__(256, 2) void gemm3(
    const u16* __restrict__ Ah, const u16* __restrict__ Bh,
    const u16* __restrict__ Bl, const float* __restrict__ bias,
    const float* __restrict__ xorig, const float* __restrict__ wadd,
    float* __restrict__ outp) {
  extern __shared__ char smem[];
  char* sA = smem;
  char* sBh = smem + 16384;
  char* sBl = smem + 32768;
  const int tid = threadIdx.x;
  const int l = tid & 63;
  const int w = tid >> 6;
  const int wm = w & 1, wn = w >> 1;
  const int lr = l & 15, lk = l >> 4;
  const int sx = lr & 7;
  const int bid = blockIdx.x;
  const int lin = (bid & 7) * 64 + (bid >> 3);
  const int m0 = (lin >> 2) * 128, n0 = (lin & 3) * 128;
  const int srow = l >> 3;
  const int sslot = (l & 7) ^ srow;

  f32x4 acc[4][4];
#pragma unroll
  for (int i = 0; i < 4; ++i)
#pragma unroll
    for (int j = 0; j < 4; ++j) acc[i][j] = (f32x4){0.f, 0.f, 0.f, 0.f};

  for (int k0 = 0; k0 < 1024; k0 += 64) {
    const bool lo = (k0 < 512);
#pragma unroll
    for (int pp = 0; pp < 4; ++pp) {
      int c = pp * 4 + w;
      int row = c * 8 + srow;
      int loff = c * 1024;
      size_t gob = (size_t)(n0 + row) * 1024 + k0 + sslot * 8;
      size_t goa = (size_t)(m0 + row) * 1024 + k0 + sslot * 8;
      __builtin_amdgcn_global_load_lds(
          (const __attribute__((address_space(1))) void*)(Bh + gob),
          (__attribute__((address_space(3))) void*)(sBh + loff), 16, 0, 0);
      __builtin_amdgcn_global_load_lds(
          (const __attribute__((address_space(1))) void*)(Ah + goa),
          (__attribute__((address_space(3))) void*)(sA + loff), 16, 0, 0);
      if (lo) {
        __builtin_amdgcn_global_load_lds(
            (const __attribute__((address_space(1))) void*)(Bl + gob),
            (__attribute__((address_space(3))) void*)(sBl + loff), 16, 0, 0);
      }
    }
    __syncthreads();
#pragma unroll
    for (int ks = 0; ks < 2; ++ks) {
      bf16x8 av[4], bv[4];
#pragma unroll
      for (int i = 0; i < 4; ++i)
        av[i] = *(const bf16x8*)(sA + (wm * 64 + i * 16 + lr) * 128 +
                                 (((ks * 4 + lk) ^ sx) * 16));
#pragma unroll
      for (int j = 0; j < 4; ++j)
        bv[j] = *(const bf16x8*)(sBh + (wn * 64 + j * 16 + lr) * 128 +
                                 (((ks * 4 + lk) ^ sx) * 16));
#pragma unroll
      for (int i = 0; i < 4; ++i)
#pragma unroll
        for (int j = 0; j < 4; ++j)
          acc[i][j] = __builtin_amdgcn_mfma_f32_16x16x32_bf16(av[i], bv[j],
                                                              acc[i][j], 0, 0, 0);
      if (lo) {
#pragma unroll
        for (int j = 0; j < 4; ++j)
          bv[j] = *(const bf16x8*)(sBl + (wn * 64 + j * 16 + lr) * 128 +
                                   (((ks * 4 + lk) ^ sx) * 16));
#pragma unroll
        for (int i = 0; i < 4; ++i)
#pragma unroll
          for (int j = 0; j < 4; ++j)
            acc[i][j] = __builtin_amdgcn_mfma_f32_16x16x32_bf16(
                av[i], bv[j], acc[i][j], 0, 0, 0);
      }
    }
    __syncthreads();
  }

  const int mwb = m0 + wm * 64;
  const int nwb = n0 + wn * 64;
  float w0 = wadd[0], w1 = wadd[1];
#pragma unroll
  for (int j = 0; j < 4; ++j) {
    int n = nwb + j * 16 + lr;
    float bv = bias[n];
#pragma unroll
    for (int i = 0; i < 4; ++i) {
#pragma unroll
      for (int r = 0; r < 4; ++r) {
        int m = mwb + i * 16 + lk * 4 + r;
        float v = fmaxf(acc[i][j][r] + bv, 0.f);
        outp[(size_t)m * 512 + n] = fmaf(w1, v, w0 * xorig[(size_t)m * 512 + n]);
      }
    }
  }
}

// One wave per row of 512. Newton on f(tau)=sum(relu(z-tau))-1. In place.
__global__ __launch_bounds__(256) void sparsemax_kernel(float* __restrict__ out) {
  int row = blockIdx.x * 4 + (threadIdx.x >> 6);
  int lane = threadIdx.x & 63;
  float* rp = out + (size_t)row * 512;
  f4 z0 = *(const f4*)(rp + lane * 8);
  f4 z1 = *(const f4*)(rp + lane * 8 + 4);
  float z[8];
#pragma unroll
  for (int e = 0; e < 4; ++e) {
    z[e] = z0[e];
    z[4 + e] = z1[e];
  }
  float m = z[0];
#pragma unroll
  for (int i = 1; i < 8; ++i) m = fmaxf(m, z[i]);
#pragma unroll
  for (int off = 32; off; off >>= 1) m = fmaxf(m, __shfl_xor(m, off));
  float tau = m - 1.0f;
  for (int it = 0; it < 32; ++it) {
    float s = 0.f, k = 0.f;
#pragma unroll
    for (int i = 0; i < 8; ++i) {
      if (z[i] > tau) {
        s += z[i] - tau;
        k += 1.f;
      }
    }
#pragma unroll
    for (int off = 32; off; off >>= 1) {
      s += __shfl_xor(s, off);
      k += __shfl_xor(k, off);
    }
    if (k < 0.5f) break;
    float tn = tau + (s - 1.f) / k;
    if (tn == tau) break;
    tau = tn;
  }
  float s = 0.f, k = 0.f;
#pragma unroll
  for (int i = 0; i < 8; ++i)
    if (z[i] > tau) {
      s += z[i];
      k += 1.f;
    }
#pragma unroll
  for (int off = 32; off; off >>= 1) {
    s += __shfl_xor(s, off);
    k += __shfl_xor(k, off);
  }
  float tauf = (k >= 0.5f) ? (s - 1.f) / k : (m - 1.f);
  f4 o0, o1;
#pragma unroll
  for (int e = 0; e < 4; ++e) {
    o0[e] = fmaxf(z[e] - tauf, 0.f);
    o1[e] = fmaxf(z[4 + e] - tauf, 0.f);
  }
  *(f4*)(rp + lane * 8) = o0;
  *(f4*)(rp + lane * 8 + 4) = o1;
}

extern "C" void kernel_launch(void* const* d_in, const int* in_sizes, int n_in,
                              void* d_out, int out_size, void* d_ws,
                              size_t ws_size, hipStream_t stream) {
  const float* x = (const float*)d_in[0];
  const float* W1 = (const float*)d_in[1];
  const float* b1 = (const float*)d_in[2];
  const float* centers = (const float*)d_in[3];
  const float* coefs = (const float*)d_in[4];
  const float* gamma = (const float*)d_in[5];
  const float* beta = (const float*)d_in[6];
  const float* mean = (const float*)d_in[7];
  const float* var = (const float*)d_in[8];
  const float* W_out = (const float*)d_in[9];
  const float* b_out = (const float*)d_in[10];
  const float* wadd = (const float*)d_in[11];
  float* out = (float*)d_out;

  // Workspace layout: total 69,212,160 B == round-1-proven ws_size floor.
  char* ws = (char*)d_ws;
  u16* Hh = (u16*)(ws);                      // [16384][1024] bf16 = 32 MB
  u16* Xh = (u16*)(ws + 33554432);           // [16384][512]  bf16 = 16 MB
  u16* Xb = (u16*)(ws + 50331648);           // [16384][512]  bf16 = 16 MB
  // 2 MB pool at 64 MB, time-multiplexed:
  //   phase A (G1/G2): W1th@+0, W1tl@+0.5MB, Pth@+1MB
  //   phase B (G3):    Wth @+0,  Wtl @+1MB   (transposed after G1/G2 in-stream)
  char* pool = ws + 67108864;
  u16* W1th = (u16*)(pool);
  u16* W1tl = (u16*)(pool + 524288);
  u16* Pth = (u16*)(pool + 1048576);
  u16* Wth = (u16*)(pool);
  u16* Wtl = (u16*)(pool + 1048576);
  float* cvec = (float*)(ws + 69206016);     // 2 KB
  float* scale = (float*)(ws + 69208064);    // 2 KB
  float* shift = (float*)(ws + 69210112);    // 2 KB

  prep_bn_kernel<<<2, 256, 0, stream>>>(gamma, beta, mean, var, scale, shift);
  prep_params_kernel<<<512, 64, 0, stream>>>(coefs, centers, Pth, cvec);
  transpose_split_kernel<<<dim3(16, 16), dim3(32, 8), 0, stream>>>(W1, W1th,
                                                                   W1tl, 512,
                                                                   512);
  conv_x_kernel<<<4096, 256, 0, stream>>>(x, scale, shift, Xh, Xb);

  // Merged G1+G2: one 1024-block launch, both gemms co-resident.
  gemm_fused12<<<1024, 256, 32768, stream>>>(Xh, Xb, W1th, Pth, b1, cvec, Hh);

  // W_out transpose reuses the pool -> must run after G1/G2 (stream-ordered).
  transpose_split_kernel<<<dim3(16, 32), dim3(32, 8), 0, stream>>>(W_out, Wth,
                                                                   Wtl, 1024,
                                                                   512);
  gemm3<<<512, 256, 49152, stream>>>(Hh, Wth, Wtl, b_out, x, wadd, out);
  sparsemax_kernel<<<4096, 256, 0, stream>>>(out);
}

// Round 8
// 113.977 us; speedup vs baseline: 5.4599x; 1.0732x over previous
//
#include <hip/hip_runtime.h>
#include <math.h>

typedef float f4 __attribute__((ext_vector_type(4)));
typedef float f32x4 __attribute__((ext_vector_type(4)));
typedef __bf16 bf16x8 __attribute__((ext_vector_type(8)));
typedef unsigned short u16;
typedef u16 us8 __attribute__((ext_vector_type(8)));

__device__ __forceinline__ u16 f2bf(float f) {
  unsigned u = __builtin_bit_cast(unsigned, f);
  unsigned r = u + 0x7fffu + ((u >> 16) & 1u);
  return (u16)(r >> 16);
}
__device__ __forceinline__ float bf2f(u16 h) {
  unsigned u = ((unsigned)h) << 16;
  return __builtin_bit_cast(float, u);
}

// scale[d] = rsqrt(var+eps)*gamma ; shift[d] = beta - mean*scale
__global__ __launch_bounds__(256) void prep_bn_kernel(
    const float* __restrict__ gamma, const float* __restrict__ beta,
    const float* __restrict__ mean, const float* __restrict__ var,
    float* __restrict__ scale, float* __restrict__ shift) {
  int d = blockIdx.x * blockDim.x + threadIdx.x;
  if (d < 512) {
    float s = rsqrtf(var[d] + 1e-3f) * gamma[d];
    scale[d] = s;
    shift[d] = beta[d] - mean[d] * s;
  }
}

// Pth[j][k] (bf16, [512][1024]): k<512 -> coefs^2 ; k>=512 -> -2*coefs^2*centers
// cvec[j] = sum_d coefs^2*centers^2  (fp32)
__global__ __launch_bounds__(64) void prep_params_kernel(
    const float* __restrict__ coefs, const float* __restrict__ centers,
    u16* __restrict__ pth, float* __restrict__ cvec) {
  int j = blockIdx.x;
  int l = threadIdx.x;
  int d0 = l * 8;
  f4 c0 = *(const f4*)(coefs + (size_t)j * 512 + d0);
  f4 c1 = *(const f4*)(coefs + (size_t)j * 512 + d0 + 4);
  f4 e0 = *(const f4*)(centers + (size_t)j * 512 + d0);
  f4 e1 = *(const f4*)(centers + (size_t)j * 512 + d0 + 4);
  us8 pa, pb;
  float acc = 0.f;
#pragma unroll
  for (int e = 0; e < 8; ++e) {
    float cf = (e < 4) ? c0[e] : c1[e - 4];
    float ce = (e < 4) ? e0[e] : e1[e - 4];
    float a = cf * cf;
    pa[e] = f2bf(a);
    pb[e] = f2bf(-2.f * a * ce);
    acc = fmaf(a * ce, ce, acc);
  }
  *(us8*)(pth + (size_t)j * 1024 + d0) = pa;
  *(us8*)(pth + (size_t)j * 1024 + 512 + d0) = pb;
#pragma unroll
  for (int off = 32; off; off >>= 1) acc += __shfl_xor(acc, off);
  if (l == 0) cvec[j] = acc;
}

// Transpose [K][N] fp32 -> Th (and optionally Tl) [N][K] bf16
__global__ __launch_bounds__(256) void transpose_split_kernel(
    const float* __restrict__ in, u16* __restrict__ th, u16* __restrict__ tl,
    int K, int N) {
  __shared__ float t[32][33];
  int lx = threadIdx.x;  // 32
  int ly = threadIdx.y;  // 8
  int n0 = blockIdx.x * 32, k0 = blockIdx.y * 32;
#pragma unroll
  for (int i = 0; i < 4; ++i)
    t[ly + 8 * i][lx] = in[(size_t)(k0 + ly + 8 * i) * N + n0 + lx];
  __syncthreads();
#pragma unroll
  for (int i = 0; i < 4; ++i) {
    float v = t[lx][ly + 8 * i];
    u16 h = f2bf(v);
    th[(size_t)(n0 + ly + 8 * i) * K + k0 + lx] = h;
    if (tl) {
      u16 lo = f2bf(v - bf2f(h));
      tl[(size_t)(n0 + ly + 8 * i) * K + k0 + lx] = lo;
    }
  }
}

// x [16384][512] fp32 -> Xh = bf16(x), Xb = bf16(x*scale+shift)
__global__ __launch_bounds__(256) void conv_x_kernel(
    const float* __restrict__ x, const float* __restrict__ scale,
    const float* __restrict__ shift, u16* __restrict__ xh,
    u16* __restrict__ xb) {
  int gid = blockIdx.x * 256 + threadIdx.x;
  int m = gid >> 6;
  int d0 = (gid & 63) * 8;
  f4 v0 = *(const f4*)(x + (size_t)m * 512 + d0);
  f4 v1 = *(const f4*)(x + (size_t)m * 512 + d0 + 4);
  f4 s0 = *(const f4*)(scale + d0);
  f4 s1 = *(const f4*)(scale + d0 + 4);
  f4 h0 = *(const f4*)(shift + d0);
  f4 h1 = *(const f4*)(shift + d0 + 4);
  us8 oh, ob;
#pragma unroll
  for (int e = 0; e < 8; ++e) {
    float xv = (e < 4) ? v0[e] : v1[e - 4];
    float sc = (e < 4) ? s0[e] : s1[e - 4];
    float sh = (e < 4) ? h0[e] : h1[e - 4];
    oh[e] = f2bf(xv);
    ob[e] = f2bf(fmaf(xv, sc, sh));
  }
  *(us8*)(xh + (size_t)m * 512 + d0) = oh;
  *(us8*)(xb + (size_t)m * 512 + d0) = ob;
}

// Merged G1+G2: 1024 blocks, 128x128 tiles, BK=64, 1-pass each.
// L = p*8 + g'*4 + n ; g = g'^1 so the K=1024 (G2) blocks dispatch first
// (longest-job-first makespan). XCD swizzle L=(bid&7)*128+(bid>>3).
__global__ __launch_bounds__(256, 4) void gemm_fused12(
    const u16* __restrict__ Xh, const u16* __restrict__ Xb,
    const u16* __restrict__ W1th, const u16* __restrict__ Pth,
    const float* __restrict__ b1, const float* __restrict__ cvec,
    u16* __restrict__ Hout) {
  extern __shared__ char smem[];
  char* sA = smem;
  char* sBh = smem + 16384;
  const int tid = threadIdx.x;
  const int l = tid & 63;
  const int w = tid >> 6;
  const int wm = w & 1, wn = w >> 1;
  const int lr = l & 15, lk = l >> 4;
  const int sx = lr & 7;
  const int bid = blockIdx.x;
  const int L = (bid & 7) * 128 + (bid >> 3);
  const int p = L >> 3;
  const int g = ((L >> 2) & 1) ^ 1;  // long (G2) blocks first
  const int n = L & 3;
  const int m0 = p * 128, n0 = n * 128;
  const int Kg = g ? 1024 : 512;
  const u16* Bmat = g ? Pth : W1th;
  const u16* Amat = g ? Xb : Xh;
  const int srow = l >> 3;
  const int sslot = (l & 7) ^ srow;

  f32x4 acc[4][4];
#pragma unroll
  for (int i = 0; i < 4; ++i)
#pragma unroll
    for (int j = 0; j < 4; ++j) acc[i][j] = (f32x4){0.f, 0.f, 0.f, 0.f};

  for (int k0 = 0; k0 < Kg; k0 += 64) {
#pragma unroll
    for (int pp = 0; pp < 4; ++pp) {
      int c = pp * 4 + w;
      int row = c * 8 + srow;
      int loff = c * 1024;
      size_t gob = (size_t)(n0 + row) * Kg + k0 + sslot * 8;
      __builtin_amdgcn_global_load_lds(
          (const __attribute__((address_space(1))) void*)(Bmat + gob),
          (__attribute__((address_space(3))) void*)(sBh + loff), 16, 0, 0);
      if (g) {
        int kb = (k0 < 512) ? k0 : (k0 - 512);
        us8 v = *(const us8*)(Amat + (size_t)(m0 + row) * 512 + kb + sslot * 8);
        us8 o;
        if (k0 < 512) {
#pragma unroll
          for (int e = 0; e < 8; ++e) {
            float f = bf2f(v[e]);
            o[e] = f2bf(f * f);
          }
        } else {
          o = v;
        }
        *(us8*)(sA + loff + l * 16) = o;
      } else {
        size_t goa = (size_t)(m0 + row) * 512 + k0 + sslot * 8;
        __builtin_amdgcn_global_load_lds(
            (const __attribute__((address_space(1))) void*)(Amat + goa),
            (__attribute__((address_space(3))) void*)(sA + loff), 16, 0, 0);
      }
    }
    __syncthreads();
#pragma unroll
    for (int ks = 0; ks < 2; ++ks) {
      bf16x8 av[4], bv[4];
#pragma unroll
      for (int i = 0; i < 4; ++i)
        av[i] = *(const bf16x8*)(sA + (wm * 64 + i * 16 + lr) * 128 +
                                 (((ks * 4 + lk) ^ sx) * 16));
#pragma unroll
      for (int j = 0; j < 4; ++j)
        bv[j] = *(const bf16x8*)(sBh + (wn * 64 + j * 16 + lr) * 128 +
                                 (((ks * 4 + lk) ^ sx) * 16));
#pragma unroll
      for (int i = 0; i < 4; ++i)
#pragma unroll
        for (int j = 0; j < 4; ++j)
          acc[i][j] = __builtin_amdgcn_mfma_f32_16x16x32_bf16(av[i], bv[j],
                                                              acc[i][j], 0, 0, 0);
    }
    __syncthreads();
  }

  const int mwb = m0 + wm * 64;
  const int nwb = n0 + wn * 64;
  const float* bias = g ? cvec : b1;
#pragma unroll
  for (int j = 0; j < 4; ++j) {
    int nn = nwb + j * 16 + lr;
    float bv = bias[nn];
#pragma unroll
    for (int i = 0; i < 4; ++i) {
#pragma unroll
      for (int r = 0; r < 4; ++r) {
        int m = mwb + i * 16 + lk * 4 + r;
        float v = acc[i][j][r] + bv;
        v = g ? fmaxf(1.f - v, 0.f) : fmaxf(v, 0.f);
        Hout[(size_t)m * 1024 + g * 512 + nn] = f2bf(v);
      }
    }
  }
}

// G3: out = w0*x + w1*relu(Hh @ Wth^T + b_out). K=1024, 128x128, BK=64,
// hi-only, double-buffered 2-phase: stage(t+1) issued BEFORE compute(t),
// single __syncthreads per K-step -> load latency hides under MFMA.
// LDS 64KB: sA[2]@0/16K, sB[2]@32K/48K. 512 blocks, XCD swizzle.
__global__ __launch_bounds__(256, 2) void gemm3(
    const u16* __restrict__ Ah, const u16* __restrict__ Bh,
    const float* __restrict__ bias, const float* __restrict__ xorig,
    const float* __restrict__ wadd, float* __restrict__ outp) {
  extern __shared__ char smem[];
  const int tid = threadIdx.x;
  const int l = tid & 63;
  const int w = tid >> 6;
  const int wm = w & 1, wn = w >> 1;
  const int lr = l & 15, lk = l >> 4;
  const int sx = lr & 7;
  const int bid = blockIdx.x;
  const int lin = (bid & 7) * 64 + (bid >> 3);
  const int m0 = (lin >> 2) * 128, n0 = (lin & 3) * 128;
  const int srow = l >> 3;
  const int sslot = (l & 7) ^ srow;

  f32x4 acc[4][4];
#pragma unroll
  for (int i = 0; i < 4; ++i)
#pragma unroll
    for (int j = 0; j < 4; ++j) acc[i][j] = (f32x4){0.f, 0.f, 0.f, 0.f};

#define G3_STAGE(buf, k0)                                                     \
  {                                                                           \
    char* dA = smem + (buf)*16384;                                            \
    char* dB = smem + 32768 + (buf)*16384;                                    \
    _Pragma("unroll") for (int pp = 0; pp < 4; ++pp) {                        \
      int c = pp * 4 + w;                                                     \
      int row = c * 8 + srow;                                                 \
      int loff = c * 1024;                                                    \
      size_t gob = (size_t)(n0 + row) * 1024 + (k0) + sslot * 8;              \
      size_t goa = (size_t)(m0 + row) * 1024 + (k0) + sslot * 8;              \
      __builtin_amdgcn_global_load_lds(                                       \
          (const __attribute__((address_space(1))) void*)(Bh + gob),          \
          (__attribute__((address_space(3))) void*)(dB + loff), 16, 0, 0);    \
      __builtin_amdgcn_global_load_lds(                                       \
          (const __attribute__((address_space(1))) void*)(Ah + goa),          \
          (__attribute__((address_space(3))) void*)(dA + loff), 16, 0, 0);    \
    }                                                                         \
  }

  G3_STAGE(0, 0);
  __syncthreads();
  for (int t = 0; t < 16; ++t) {
    if (t + 1 < 16) G3_STAGE((t + 1) & 1, (t + 1) * 64);
    const char* sA = smem + (t & 1) * 16384;
    const char* sB = smem + 32768 + (t & 1) * 16384;
#pragma unroll
    for (int ks = 0; ks < 2; ++ks) {
      bf16x8 av[4], bv[4];
#pragma unroll
      for (int i = 0; i < 4; ++i)
        av[i] = *(const bf16x8*)(sA + (wm * 64 + i * 16 + lr) * 128 +
                                 (((ks * 4 + lk) ^ sx) * 16));
#pragma unroll
      for (int j = 0; j < 4; ++j)
        bv[j] = *(const bf16x8*)(sB + (wn * 64 + j * 16 + lr) * 128 +
                                 (((ks * 4 + lk) ^ sx) * 16));
#pragma unroll
      for (int i = 0; i < 4; ++i)
#pragma unroll
        for (int j = 0; j < 4; ++j)
          acc[i][j] = __builtin_amdgcn_mfma_f32_16x16x32_bf16(av[i], bv[j],
                                                              acc[i][j], 0, 0, 0);
    }
    __syncthreads();
  }
#undef G3_STAGE

  const int mwb = m0 + wm * 64;
  const int nwb = n0 + wn * 64;
  float w0 = wadd[0], w1 = wadd[1];
#pragma unroll
  for (int j = 0; j < 4; ++j) {
    int n = nwb + j * 16 + lr;
    float bv = bias[n];
#pragma unroll
    for (int i = 0; i < 4; ++i) {
#pragma unroll
      for (int r = 0; r < 4; ++r) {
        int m = mwb + i * 16 + lk * 4 + r;
        float v = fmaxf(acc[i][j][r] + bv, 0.f);
        outp[(size_t)m * 512 + n] = fmaf(w1, v, w0 * xorig[(size_t)m * 512 + n]);
      }
    }
  }
}

// One wave per row of 512. Newton on f(tau)=sum(relu(z-tau))-1. In place.
__global__ __launch_bounds__(256) void sparsemax_kernel(float* __restrict__ out) {
  int row = blockIdx.x * 4 + (threadIdx.x >> 6);
  int lane = threadIdx.x & 63;
  float* rp = out + (size_t)row * 512;
  f4 z0 = *(const f4*)(rp + lane * 8);
  f4 z1 = *(const f4*)(rp + lane * 8 + 4);
  float z[8];
#pragma unroll
  for (int e = 0; e < 4; ++e) {
    z[e] = z0[e];
    z[4 + e] = z1[e];
  }
  float m = z[0];
#pragma unroll
  for (int i = 1; i < 8; ++i) m = fmaxf(m, z[i]);
#pragma unroll
  for (int off = 32; off; off >>= 1) m = fmaxf(m, __shfl_xor(m, off));
  float tau = m - 1.0f;
  for (int it = 0; it < 32; ++it) {
    float s = 0.f, k = 0.f;
#pragma unroll
    for (int i = 0; i < 8; ++i) {
      if (z[i] > tau) {
        s += z[i] - tau;
        k += 1.f;
      }
    }
#pragma unroll
    for (int off = 32; off; off >>= 1) {
      s += __shfl_xor(s, off);
      k += __shfl_xor(k, off);
    }
    if (k < 0.5f) break;
    float tn = tau + (s - 1.f) / k;
    if (tn == tau) break;
    tau = tn;
  }
  float s = 0.f, k = 0.f;
#pragma unroll
  for (int i = 0; i < 8; ++i)
    if (z[i] > tau) {
      s += z[i];
      k += 1.f;
    }
#pragma unroll
  for (int off = 32; off; off >>= 1) {
    s += __shfl_xor(s, off);
    k += __shfl_xor(k, off);
  }
  float tauf = (k >= 0.5f) ? (s - 1.f) / k : (m - 1.f);
  f4 o0, o1;
#pragma unroll
  for (int e = 0; e < 4; ++e) {
    o0[e] = fmaxf(z[e] - tauf, 0.f);
    o1[e] = fmaxf(z[4 + e] - tauf, 0.f);
  }
  *(f4*)(rp + lane * 8) = o0;
  *(f4*)(rp + lane * 8 + 4) = o1;
}

extern "C" void kernel_launch(void* const* d_in, const int* in_sizes, int n_in,
                              void* d_out, int out_size, void* d_ws,
                              size_t ws_size, hipStream_t stream) {
  const float* x = (const float*)d_in[0];
  const float* W1 = (const float*)d_in[1];
  const float* b1 = (const float*)d_in[2];
  const float* centers = (const float*)d_in[3];
  const float* coefs = (const float*)d_in[4];
  const float* gamma = (const float*)d_in[5];
  const float* beta = (const float*)d_in[6];
  const float* mean = (const float*)d_in[7];
  const float* var = (const float*)d_in[8];
  const float* W_out = (const float*)d_in[9];
  const float* b_out = (const float*)d_in[10];
  const float* wadd = (const float*)d_in[11];
  float* out = (float*)d_out;

  // Workspace layout: total 69,212,160 B == round-1-proven ws_size floor.
  char* ws = (char*)d_ws;
  u16* Hh = (u16*)(ws);                      // [16384][1024] bf16 = 32 MB
  u16* Xh = (u16*)(ws + 33554432);           // [16384][512]  bf16 = 16 MB
  u16* Xb = (u16*)(ws + 50331648);           // [16384][512]  bf16 = 16 MB
  // 2 MB pool at 64 MB, time-multiplexed:
  //   phase A (G1/G2): W1th@+0, Pth@+1MB
  //   phase B (G3):    Wth @+0           (transposed after G1/G2 in-stream)
  char* pool = ws + 67108864;
  u16* W1th = (u16*)(pool);
  u16* Pth = (u16*)(pool + 1048576);
  u16* Wth = (u16*)(pool);
  float* cvec = (float*)(ws + 69206016);     // 2 KB
  float* scale = (float*)(ws + 69208064);    // 2 KB
  float* shift = (float*)(ws + 69210112);    // 2 KB

  prep_bn_kernel<<<2, 256, 0, stream>>>(gamma, beta, mean, var, scale, shift);
  prep_params_kernel<<<512, 64, 0, stream>>>(coefs, centers, Pth, cvec);
  transpose_split_kernel<<<dim3(16, 16), dim3(32, 8), 0, stream>>>(
      W1, W1th, nullptr, 512, 512);
  conv_x_kernel<<<4096, 256, 0, stream>>>(x, scale, shift, Xh, Xb);

  // Merged G1+G2: one 1024-block launch, both gemms co-resident.
  gemm_fused12<<<1024, 256, 32768, stream>>>(Xh, Xb, W1th, Pth, b1, cvec, Hh);

  // W_out transpose reuses the pool -> must run after G1/G2 (stream-ordered).
  transpose_split_kernel<<<dim3(16, 32), dim3(32, 8), 0, stream>>>(
      W_out, Wth, nullptr, 1024, 512);
  gemm3<<<512, 256, 65536, stream>>>(Hh, Wth, b_out, x, wadd, out);
  sparsemax_kernel<<<4096, 256, 0, stream>>>(out);
}

// Round 9
// 111.190 us; speedup vs baseline: 5.5967x; 1.0251x over previous
//
#include <hip/hip_runtime.h>
#include <math.h>

typedef float f4 __attribute__((ext_vector_type(4)));
typedef float f32x4 __attribute__((ext_vector_type(4)));
typedef __bf16 bf16x8 __attribute__((ext_vector_type(8)));
typedef unsigned short u16;
typedef u16 us8 __attribute__((ext_vector_type(8)));

__device__ __forceinline__ u16 f2bf(float f) {
  unsigned u = __builtin_bit_cast(unsigned, f);
  unsigned r = u + 0x7fffu + ((u >> 16) & 1u);
  return (u16)(r >> 16);
}
__device__ __forceinline__ float bf2f(u16 h) {
  unsigned u = ((unsigned)h) << 16;
  return __builtin_bit_cast(float, u);
}

// scale[d] = rsqrt(var+eps)*gamma ; shift[d] = beta - mean*scale
__global__ __launch_bounds__(256) void prep_bn_kernel(
    const float* __restrict__ gamma, const float* __restrict__ beta,
    const float* __restrict__ mean, const float* __restrict__ var,
    float* __restrict__ scale, float* __restrict__ shift) {
  int d = blockIdx.x * blockDim.x + threadIdx.x;
  if (d < 512) {
    float s = rsqrtf(var[d] + 1e-3f) * gamma[d];
    scale[d] = s;
    shift[d] = beta[d] - mean[d] * s;
  }
}

// Pth[j][k] (bf16, [512][1024]): k<512 -> coefs^2 ; k>=512 -> -2*coefs^2*centers
// cvec[j] = sum_d coefs^2*centers^2  (fp32)
__global__ __launch_bounds__(64) void prep_params_kernel(
    const float* __restrict__ coefs, const float* __restrict__ centers,
    u16* __restrict__ pth, float* __restrict__ cvec) {
  int j = blockIdx.x;
  int l = threadIdx.x;
  int d0 = l * 8;
  f4 c0 = *(const f4*)(coefs + (size_t)j * 512 + d0);
  f4 c1 = *(const f4*)(coefs + (size_t)j * 512 + d0 + 4);
  f4 e0 = *(const f4*)(centers + (size_t)j * 512 + d0);
  f4 e1 = *(const f4*)(centers + (size_t)j * 512 + d0 + 4);
  us8 pa, pb;
  float acc = 0.f;
#pragma unroll
  for (int e = 0; e < 8; ++e) {
    float cf = (e < 4) ? c0[e] : c1[e - 4];
    float ce = (e < 4) ? e0[e] : e1[e - 4];
    float a = cf * cf;
    pa[e] = f2bf(a);
    pb[e] = f2bf(-2.f * a * ce);
    acc = fmaf(a * ce, ce, acc);
  }
  *(us8*)(pth + (size_t)j * 1024 + d0) = pa;
  *(us8*)(pth + (size_t)j * 1024 + 512 + d0) = pb;
#pragma unroll
  for (int off = 32; off; off >>= 1) acc += __shfl_xor(acc, off);
  if (l == 0) cvec[j] = acc;
}

// Transpose [K][N] fp32 -> Th [N][K] bf16 (hi only)
__global__ __launch_bounds__(256) void transpose_split_kernel(
    const float* __restrict__ in, u16* __restrict__ th, int K, int N) {
  __shared__ float t[32][33];
  int lx = threadIdx.x;  // 32
  int ly = threadIdx.y;  // 8
  int n0 = blockIdx.x * 32, k0 = blockIdx.y * 32;
#pragma unroll
  for (int i = 0; i < 4; ++i)
    t[ly + 8 * i][lx] = in[(size_t)(k0 + ly + 8 * i) * N + n0 + lx];
  __syncthreads();
#pragma unroll
  for (int i = 0; i < 4; ++i) {
    float v = t[lx][ly + 8 * i];
    th[(size_t)(n0 + ly + 8 * i) * K + k0 + lx] = f2bf(v);
  }
}

// x [16384][512] fp32 -> Xh = bf16(x), Xb = bf16(x*scale+shift)
__global__ __launch_bounds__(256) void conv_x_kernel(
    const float* __restrict__ x, const float* __restrict__ scale,
    const float* __restrict__ shift, u16* __restrict__ xh,
    u16* __restrict__ xb) {
  int gid = blockIdx.x * 256 + threadIdx.x;
  int m = gid >> 6;
  int d0 = (gid & 63) * 8;
  f4 v0 = *(const f4*)(x + (size_t)m * 512 + d0);
  f4 v1 = *(const f4*)(x + (size_t)m * 512 + d0 + 4);
  f4 s0 = *(const f4*)(scale + d0);
  f4 s1 = *(const f4*)(scale + d0 + 4);
  f4 h0 = *(const f4*)(shift + d0);
  f4 h1 = *(const f4*)(shift + d0 + 4);
  us8 oh, ob;
#pragma unroll
  for (int e = 0; e < 8; ++e) {
    float xv = (e < 4) ? v0[e] : v1[e - 4];
    float sc = (e < 4) ? s0[e] : s1[e - 4];
    float sh = (e < 4) ? h0[e] : h1[e - 4];
    oh[e] = f2bf(xv);
    ob[e] = f2bf(fmaf(xv, sc, sh));
  }
  *(us8*)(xh + (size_t)m * 512 + d0) = oh;
  *(us8*)(xb + (size_t)m * 512 + d0) = ob;
}

// Merged G1+G2, double-buffered 2-phase. 1024 blocks, 128x128, BK=64.
// LDS 64KB: bufA[2]@0/16K, bufB[2]@32K/48K. 2 blocks/CU.
// L=(bid&7)*128+(bid>>3); L = p*8 + g'*4 + n, g=g'^1 (K=1024 G2 first).
// g==0: A = Xh via global_load_lds. g==1: A built from Xb via T14 async
// reg-stage (issue loads early, square+ds_write after MFMA phase).
__global__ __launch_bounds__(256, 2) void gemm_fused12(
    const u16* __restrict__ Xh, const u16* __restrict__ Xb,
    const u16* __restrict__ W1th, const u16* __restrict__ Pth,
    const float* __restrict__ b1, const float* __restrict__ cvec,
    u16* __restrict__ Hout) {
  extern __shared__ char smem[];
  const int tid = threadIdx.x;
  const int l = tid & 63;
  const int w = tid >> 6;
  const int wm = w & 1, wn = w >> 1;
  const int lr = l & 15, lk = l >> 4;
  const int sx = lr & 7;
  const int bid = blockIdx.x;
  const int L = (bid & 7) * 128 + (bid >> 3);
  const int p = L >> 3;
  const int g = ((L >> 2) & 1) ^ 1;
  const int n = L & 3;
  const int m0 = p * 128, n0 = n * 128;
  const int Kg = g ? 1024 : 512;
  const int nt = g ? 16 : 8;
  const u16* Bmat = g ? Pth : W1th;
  const u16* Amat = g ? Xb : Xh;
  const int srow = l >> 3;
  const int sslot = (l & 7) ^ srow;

  f32x4 acc[4][4];
#pragma unroll
  for (int i = 0; i < 4; ++i)
#pragma unroll
    for (int j = 0; j < 4; ++j) acc[i][j] = (f32x4){0.f, 0.f, 0.f, 0.f};

  // prologue: stage tile 0 into buffer 0
  if (g) {
#pragma unroll
    for (int pp = 0; pp < 4; ++pp) {
      int c = pp * 4 + w;
      int row = c * 8 + srow;
      us8 v = *(const us8*)(Amat + (size_t)(m0 + row) * 512 + sslot * 8);
      us8 o;
#pragma unroll
      for (int e = 0; e < 8; ++e) {
        float f = bf2f(v[e]);
        o[e] = f2bf(f * f);
      }
      *(us8*)(smem + c * 1024 + l * 16) = o;
    }
  } else {
#pragma unroll
    for (int pp = 0; pp < 4; ++pp) {
      int c = pp * 4 + w;
      int row = c * 8 + srow;
      size_t goa = (size_t)(m0 + row) * 512 + sslot * 8;
      __builtin_amdgcn_global_load_lds(
          (const __attribute__((address_space(1))) void*)(Amat + goa),
          (__attribute__((address_space(3))) void*)(smem + c * 1024), 16, 0, 0);
    }
  }
#pragma unroll
  for (int pp = 0; pp < 4; ++pp) {
    int c = pp * 4 + w;
    int row = c * 8 + srow;
    size_t gob = (size_t)(n0 + row) * Kg + sslot * 8;
    __builtin_amdgcn_global_load_lds(
        (const __attribute__((address_space(1))) void*)(Bmat + gob),
        (__attribute__((address_space(3))) void*)(smem + 32768 + c * 1024), 16,
        0, 0);
  }
  __syncthreads();

  for (int t = 0; t < nt; ++t) {
    const int cur = t & 1, nxt = cur ^ 1;
    const int k1 = (t + 1) * 64;
    const bool more = (t + 1 < nt);
    us8 areg[4];
    if (more) {
      if (g) {
        int kb = (k1 < 512) ? k1 : (k1 - 512);
#pragma unroll
        for (int pp = 0; pp < 4; ++pp) {
          int c = pp * 4 + w;
          int row = c * 8 + srow;
          areg[pp] =
              *(const us8*)(Amat + (size_t)(m0 + row) * 512 + kb + sslot * 8);
        }
      } else {
#pragma unroll
        for (int pp = 0; pp < 4; ++pp) {
          int c = pp * 4 + w;
          int row = c * 8 + srow;
          size_t goa = (size_t)(m0 + row) * 512 + k1 + sslot * 8;
          __builtin_amdgcn_global_load_lds(
              (const __attribute__((address_space(1))) void*)(Amat + goa),
              (__attribute__((address_space(3))) void*)(smem + nxt * 16384 +
                                                        c * 1024),
              16, 0, 0);
        }
      }
#pragma unroll
      for (int pp = 0; pp < 4; ++pp) {
        int c = pp * 4 + w;
        int row = c * 8 + srow;
        size_t gob = (size_t)(n0 + row) * Kg + k1 + sslot * 8;
        __builtin_amdgcn_global_load_lds(
            (const __attribute__((address_space(1))) void*)(Bmat + gob),
            (__attribute__((address_space(3))) void*)(smem + 32768 +
                                                      nxt * 16384 + c * 1024),
            16, 0, 0);
      }
    }
    const char* sA = smem + cur * 16384;
    const char* sB = smem + 32768 + cur * 16384;
#pragma unroll
    for (int ks = 0; ks < 2; ++ks) {
      bf16x8 av[4], bv[4];
#pragma unroll
      for (int i = 0; i < 4; ++i)
        av[i] = *(const bf16x8*)(sA + (wm * 64 + i * 16 + lr) * 128 +
                                 (((ks * 4 + lk) ^ sx) * 16));
#pragma unroll
      for (int j = 0; j < 4; ++j)
        bv[j] = *(const bf16x8*)(sB + (wn * 64 + j * 16 + lr) * 128 +
                                 (((ks * 4 + lk) ^ sx) * 16));
#pragma unroll
      for (int i = 0; i < 4; ++i)
#pragma unroll
        for (int j = 0; j < 4; ++j)
          acc[i][j] = __builtin_amdgcn_mfma_f32_16x16x32_bf16(av[i], bv[j],
                                                              acc[i][j], 0, 0, 0);
    }
    if (more && g) {
      // T14 write-late: convert staged regs, write into next A buffer.
      const bool sq = (k1 < 512);
#pragma unroll
      for (int pp = 0; pp < 4; ++pp) {
        int c = pp * 4 + w;
        us8 o;
        if (sq) {
#pragma unroll
          for (int e = 0; e < 8; ++e) {
            float f = bf2f(areg[pp][e]);
            o[e] = f2bf(f * f);
          }
        } else {
          o = areg[pp];
        }
        *(us8*)(smem + nxt * 16384 + c * 1024 + l * 16) = o;
      }
    }
    __syncthreads();
  }

  const int mwb = m0 + wm * 64;
  const int nwb = n0 + wn * 64;
  const float* bias = g ? cvec : b1;
#pragma unroll
  for (int j = 0; j < 4; ++j) {
    int nn = nwb + j * 16 + lr;
    float bv = bias[nn];
#pragma unroll
    for (int i = 0; i < 4; ++i) {
#pragma unroll
      for (int r = 0; r < 4; ++r) {
        int m = mwb + i * 16 + lk * 4 + r;
        float v = acc[i][j][r] + bv;
        v = g ? fmaxf(1.f - v, 0.f) : fmaxf(v, 0.f);
        Hout[(size_t)m * 1024 + g * 512 + nn] = f2bf(v);
      }
    }
  }
}

// G3: out = w0*x + w1*relu(Hh @ Wth^T + b_out). K=1024, 128x128, BK=64,
// hi-only, double-buffered 2-phase, LDS 64KB. 512 blocks, XCD swizzle.
__global__ __launch_bounds__(256, 2) void gemm3(
    const u16* __restrict__ Ah, const u16* __restrict__ Bh,
    const float* __restrict__ bias, const float* __restrict__ xorig,
    const float* __restrict__ wadd, float* __restrict__ outp) {
  extern __shared__ char smem[];
  const int tid = threadIdx.x;
  const int l = tid & 63;
  const int w = tid >> 6;
  const int wm = w & 1, wn = w >> 1;
  const int lr = l & 15, lk = l >> 4;
  const int sx = lr & 7;
  const int bid = blockIdx.x;
  const int lin = (bid & 7) * 64 + (bid >> 3);
  const int m0 = (lin >> 2) * 128, n0 = (lin & 3) * 128;
  const int srow = l >> 3;
  const int sslot = (l & 7) ^ srow;

  f32x4 acc[4][4];
#pragma unroll
  for (int i = 0; i < 4; ++i)
#pragma unroll
    for (int j = 0; j < 4; ++j) acc[i][j] = (f32x4){0.f, 0.f, 0.f, 0.f};

#define G3_STAGE(buf, k0)                                                     \
  {                                                                           \
    char* dA = smem + (buf)*16384;                                            \
    char* dB = smem + 32768 + (buf)*16384;                                    \
    _Pragma("unroll") for (int pp = 0; pp < 4; ++pp) {                        \
      int c = pp * 4 + w;                                                     \
      int row = c * 8 + srow;                                                 \
      int loff = c * 1024;                                                    \
      size_t gob = (size_t)(n0 + row) * 1024 + (k0) + sslot * 8;              \
      size_t goa = (size_t)(m0 + row) * 1024 + (k0) + sslot * 8;              \
      __builtin_amdgcn_global_load_lds(                                       \
          (const __attribute__((address_space(1))) void*)(Bh + gob),          \
          (__attribute__((address_space(3))) void*)(dB + loff), 16, 0, 0);    \
      __builtin_amdgcn_global_load_lds(                                       \
          (const __attribute__((address_space(1))) void*)(Ah + goa),          \
          (__attribute__((address_space(3))) void*)(dA + loff), 16, 0, 0);    \
    }                                                                         \
  }

  G3_STAGE(0, 0);
  __syncthreads();
  for (int t = 0; t < 16; ++t) {
    if (t + 1 < 16) G3_STAGE((t + 1) & 1, (t + 1) * 64);
    const char* sA = smem + (t & 1) * 16384;
    const char* sB = smem + 32768 + (t & 1) * 16384;
#pragma unroll
    for (int ks = 0; ks < 2; ++ks) {
      bf16x8 av[4], bv[4];
#pragma unroll
      for (int i = 0; i < 4; ++i)
        av[i] = *(const bf16x8*)(sA + (wm * 64 + i * 16 + lr) * 128 +
                                 (((ks * 4 + lk) ^ sx) * 16));
#pragma unroll
      for (int j = 0; j < 4; ++j)
        bv[j] = *(const bf16x8*)(sB + (wn * 64 + j * 16 + lr) * 128 +
                                 (((ks * 4 + lk) ^ sx) * 16));
#pragma unroll
      for (int i = 0; i < 4; ++i)
#pragma unroll
        for (int j = 0; j < 4; ++j)
          acc[i][j] = __builtin_amdgcn_mfma_f32_16x16x32_bf16(av[i], bv[j],
                                                              acc[i][j], 0, 0, 0);
    }
    __syncthreads();
  }
#undef G3_STAGE

  const int mwb = m0 + wm * 64;
  const int nwb = n0 + wn * 64;
  float w0 = wadd[0], w1 = wadd[1];
#pragma unroll
  for (int j = 0; j < 4; ++j) {
    int n = nwb + j * 16 + lr;
    float bv = bias[n];
#pragma unroll
    for (int i = 0; i < 4; ++i) {
#pragma unroll
      for (int r = 0; r < 4; ++r) {
        int m = mwb + i * 16 + lk * 4 + r;
        float v = fmaxf(acc[i][j][r] + bv, 0.f);
        outp[(size_t)m * 512 + n] = fmaf(w1, v, w0 * xorig[(size_t)m * 512 + n]);
      }
    }
  }
}

// One wave per row of 512. Newton on f(tau)=sum(relu(z-tau))-1. In place.
__global__ __launch_bounds__(256) void sparsemax_kernel(float* __restrict__ out) {
  int row = blockIdx.x * 4 + (threadIdx.x >> 6);
  int lane = threadIdx.x & 63;
  float* rp = out + (size_t)row * 512;
  f4 z0 = *(const f4*)(rp + lane * 8);
  f4 z1 = *(const f4*)(rp + lane * 8 + 4);
  float z[8];
#pragma unroll
  for (int e = 0; e < 4; ++e) {
    z[e] = z0[e];
    z[4 + e] = z1[e];
  }
  float m = z[0];
#pragma unroll
  for (int i = 1; i < 8; ++i) m = fmaxf(m, z[i]);
#pragma unroll
  for (int off = 32; off; off >>= 1) m = fmaxf(m, __shfl_xor(m, off));
  float tau = m - 1.0f;
  for (int it = 0; it < 32; ++it) {
    float s = 0.f, k = 0.f;
#pragma unroll
    for (int i = 0; i < 8; ++i) {
      if (z[i] > tau) {
        s += z[i] - tau;
        k += 1.f;
      }
    }
#pragma unroll
    for (int off = 32; off; off >>= 1) {
      s += __shfl_xor(s, off);
      k += __shfl_xor(k, off);
    }
    if (k < 0.5f) break;
    float tn = tau + (s - 1.f) / k;
    if (tn == tau) break;
    tau = tn;
  }
  float s = 0.f, k = 0.f;
#pragma unroll
  for (int i = 0; i < 8; ++i)
    if (z[i] > tau) {
      s += z[i];
      k += 1.f;
    }
#pragma unroll
  for (int off = 32; off; off >>= 1) {
    s += __shfl_xor(s, off);
    k += __shfl_xor(k, off);
  }
  float tauf = (k >= 0.5f) ? (s - 1.f) / k : (m - 1.f);
  f4 o0, o1;
#pragma unroll
  for (int e = 0; e < 4; ++e) {
    o0[e] = fmaxf(z[e] - tauf, 0.f);
    o1[e] = fmaxf(z[4 + e] - tauf, 0.f);
  }
  *(f4*)(rp + lane * 8) = o0;
  *(f4*)(rp + lane * 8 + 4) = o1;
}

extern "C" void kernel_launch(void* const* d_in, const int* in_sizes, int n_in,
                              void* d_out, int out_size, void* d_ws,
                              size_t ws_size, hipStream_t stream) {
  const float* x = (const float*)d_in[0];
  const float* W1 = (const float*)d_in[1];
  const float* b1 = (const float*)d_in[2];
  const float* centers = (const float*)d_in[3];
  const float* coefs = (const float*)d_in[4];
  const float* gamma = (const float*)d_in[5];
  const float* beta = (const float*)d_in[6];
  const float* mean = (const float*)d_in[7];
  const float* var = (const float*)d_in[8];
  const float* W_out = (const float*)d_in[9];
  const float* b_out = (const float*)d_in[10];
  const float* wadd = (const float*)d_in[11];
  float* out = (float*)d_out;

  // Base layout: 69,212,160 B == round-1-proven ws_size floor.
  char* ws = (char*)d_ws;
  u16* Hh = (u16*)(ws);                      // [16384][1024] bf16 = 32 MB
  u16* Xh = (u16*)(ws + 33554432);           // [16384][512]  bf16 = 16 MB
  u16* Xb = (u16*)(ws + 50331648);           // [16384][512]  bf16 = 16 MB
  char* pool = ws + 67108864;                // 2 MB
  u16* W1th = (u16*)(pool);
  u16* Pth = (u16*)(pool + 1048576);
  float* cvec = (float*)(ws + 69206016);     // 2 KB
  float* scale = (float*)(ws + 69208064);    // 2 KB
  float* shift = (float*)(ws + 69210112);    // 2 KB
  // Wth: appended at +69,212,160 when ws_size allows (early transpose, no
  // mid-stream dependency); else aliased onto pool (late transpose).
  const bool bigws = (ws_size >= (size_t)70260736);
  u16* Wth = bigws ? (u16*)(ws + 69212160) : (u16*)(pool);

  prep_bn_kernel<<<2, 256, 0, stream>>>(gamma, beta, mean, var, scale, shift);
  prep_params_kernel<<<512, 64, 0, stream>>>(coefs, centers, Pth, cvec);
  transpose_split_kernel<<<dim3(16, 16), dim3(32, 8), 0, stream>>>(W1, W1th,
                                                                   512, 512);
  if (bigws) {
    transpose_split_kernel<<<dim3(16, 32), dim3(32, 8), 0, stream>>>(
        W_out, Wth, 1024, 512);
  }
  conv_x_kernel<<<4096, 256, 0, stream>>>(x, scale, shift, Xh, Xb);

  // Merged G1+G2, double-buffered.
  gemm_fused12<<<1024, 256, 65536, stream>>>(Xh, Xb, W1th, Pth, b1, cvec, Hh);

  if (!bigws) {
    // pool reuse -> must run after fused12 (stream-ordered).
    transpose_split_kernel<<<dim3(16, 32), dim3(32, 8), 0, stream>>>(
        W_out, Wth, 1024, 512);
  }
  gemm3<<<512, 256, 65536, stream>>>(Hh, Wth, b_out, x, wadd, out);
  sparsemax_kernel<<<4096, 256, 0, stream>>>(out);
}

// Round 10
// 107.688 us; speedup vs baseline: 5.7787x; 1.0325x over previous
//
#include <hip/hip_runtime.h>
#include <math.h>

typedef float f4 __attribute__((ext_vector_type(4)));
typedef float f32x4 __attribute__((ext_vector_type(4)));
typedef __bf16 bf16x8 __attribute__((ext_vector_type(8)));
typedef unsigned short u16;
typedef u16 us8 __attribute__((ext_vector_type(8)));

__device__ __forceinline__ u16 f2bf(float f) {
  unsigned u = __builtin_bit_cast(unsigned, f);
  unsigned r = u + 0x7fffu + ((u >> 16) & 1u);
  return (u16)(r >> 16);
}
__device__ __forceinline__ float bf2f(u16 h) {
  unsigned u = ((unsigned)h) << 16;
  return __builtin_bit_cast(float, u);
}

// scale[d] = rsqrt(var+eps)*gamma ; shift[d] = beta - mean*scale
__global__ __launch_bounds__(256) void prep_bn_kernel(
    const float* __restrict__ gamma, const float* __restrict__ beta,
    const float* __restrict__ mean, const float* __restrict__ var,
    float* __restrict__ scale, float* __restrict__ shift) {
  int d = blockIdx.x * blockDim.x + threadIdx.x;
  if (d < 512) {
    float s = rsqrtf(var[d] + 1e-3f) * gamma[d];
    scale[d] = s;
    shift[d] = beta[d] - mean[d] * s;
  }
}

// Pth[j][k] (bf16, [512][1024]): k<512 -> coefs^2 ; k>=512 -> -2*coefs^2*centers
// cvec[j] = sum_d coefs^2*centers^2  (fp32)
__global__ __launch_bounds__(64) void prep_params_kernel(
    const float* __restrict__ coefs, const float* __restrict__ centers,
    u16* __restrict__ pth, float* __restrict__ cvec) {
  int j = blockIdx.x;
  int l = threadIdx.x;
  int d0 = l * 8;
  f4 c0 = *(const f4*)(coefs + (size_t)j * 512 + d0);
  f4 c1 = *(const f4*)(coefs + (size_t)j * 512 + d0 + 4);
  f4 e0 = *(const f4*)(centers + (size_t)j * 512 + d0);
  f4 e1 = *(const f4*)(centers + (size_t)j * 512 + d0 + 4);
  us8 pa, pb;
  float acc = 0.f;
#pragma unroll
  for (int e = 0; e < 8; ++e) {
    float cf = (e < 4) ? c0[e] : c1[e - 4];
    float ce = (e < 4) ? e0[e] : e1[e - 4];
    float a = cf * cf;
    pa[e] = f2bf(a);
    pb[e] = f2bf(-2.f * a * ce);
    acc = fmaf(a * ce, ce, acc);
  }
  *(us8*)(pth + (size_t)j * 1024 + d0) = pa;
  *(us8*)(pth + (size_t)j * 1024 + 512 + d0) = pb;
#pragma unroll
  for (int off = 32; off; off >>= 1) acc += __shfl_xor(acc, off);
  if (l == 0) cvec[j] = acc;
}

// Transpose [K][N] fp32 -> Th [N][K] bf16 (hi only)
__global__ __launch_bounds__(256) void transpose_split_kernel(
    const float* __restrict__ in, u16* __restrict__ th, int K, int N) {
  __shared__ float t[32][33];
  int lx = threadIdx.x;  // 32
  int ly = threadIdx.y;  // 8
  int n0 = blockIdx.x * 32, k0 = blockIdx.y * 32;
#pragma unroll
  for (int i = 0; i < 4; ++i)
    t[ly + 8 * i][lx] = in[(size_t)(k0 + ly + 8 * i) * N + n0 + lx];
  __syncthreads();
#pragma unroll
  for (int i = 0; i < 4; ++i) {
    float v = t[lx][ly + 8 * i];
    th[(size_t)(n0 + ly + 8 * i) * K + k0 + lx] = f2bf(v);
  }
}

// x [16384][512] fp32 -> Xh = bf16(x), Xb = bf16(xb), Xsq = bf16(xb*xb)
// where xb = x*scale+shift. Squaring hoisted here (once) instead of in-GEMM
// (4x per element, on the MFMA critical path).
__global__ __launch_bounds__(256) void conv_x_kernel(
    const float* __restrict__ x, const float* __restrict__ scale,
    const float* __restrict__ shift, u16* __restrict__ xh,
    u16* __restrict__ xb, u16* __restrict__ xsq) {
  int gid = blockIdx.x * 256 + threadIdx.x;
  int m = gid >> 6;
  int d0 = (gid & 63) * 8;
  f4 v0 = *(const f4*)(x + (size_t)m * 512 + d0);
  f4 v1 = *(const f4*)(x + (size_t)m * 512 + d0 + 4);
  f4 s0 = *(const f4*)(scale + d0);
  f4 s1 = *(const f4*)(scale + d0 + 4);
  f4 h0 = *(const f4*)(shift + d0);
  f4 h1 = *(const f4*)(shift + d0 + 4);
  us8 oh, ob, oq;
#pragma unroll
  for (int e = 0; e < 8; ++e) {
    float xv = (e < 4) ? v0[e] : v1[e - 4];
    float sc = (e < 4) ? s0[e] : s1[e - 4];
    float sh = (e < 4) ? h0[e] : h1[e - 4];
    oh[e] = f2bf(xv);
    float xbf = fmaf(xv, sc, sh);
    ob[e] = f2bf(xbf);
    oq[e] = f2bf(xbf * xbf);
  }
  *(us8*)(xh + (size_t)m * 512 + d0) = oh;
  *(us8*)(xb + (size_t)m * 512 + d0) = ob;
  *(us8*)(xsq + (size_t)m * 512 + d0) = oq;
}

// Merged G1+G2, double-buffered 2-phase, all-global_load_lds (no in-kernel
// VALU on the staging path). 1024 blocks, 128x128, BK=64. LDS 64KB.
// L=(bid&7)*128+(bid>>3); L = p*8 + g'*4 + n, g=g'^1 (K=1024 G2 first).
// g==0: A = Xh, K=512.  g==1: A = (k<512 ? Xsq : Xb), K=1024 vs Pth.
__global__ __launch_bounds__(256, 2) void gemm_fused12(
    const u16* __restrict__ Xh, const u16* __restrict__ Xb,
    const u16* __restrict__ Xsq, const u16* __restrict__ W1th,
    const u16* __restrict__ Pth, const float* __restrict__ b1,
    const float* __restrict__ cvec, u16* __restrict__ Hout) {
  extern __shared__ char smem[];
  const int tid = threadIdx.x;
  const int l = tid & 63;
  const int w = tid >> 6;
  const int wm = w & 1, wn = w >> 1;
  const int lr = l & 15, lk = l >> 4;
  const int sx = lr & 7;
  const int bid = blockIdx.x;
  const int L = (bid & 7) * 128 + (bid >> 3);
  const int p = L >> 3;
  const int g = ((L >> 2) & 1) ^ 1;
  const int n = L & 3;
  const int m0 = p * 128, n0 = n * 128;
  const int Kg = g ? 1024 : 512;
  const int nt = g ? 16 : 8;
  const u16* Bmat = g ? Pth : W1th;
  const int srow = l >> 3;
  const int sslot = (l & 7) ^ srow;

  f32x4 acc[4][4];
#pragma unroll
  for (int i = 0; i < 4; ++i)
#pragma unroll
    for (int j = 0; j < 4; ++j) acc[i][j] = (f32x4){0.f, 0.f, 0.f, 0.f};

#define F12_STAGE(buf, k0)                                                    \
  {                                                                           \
    const u16* Asrc = g ? (((k0) < 512) ? Xsq : Xb) : Xh;                     \
    const int kb = (k0)&511;                                                  \
    char* dA = smem + (buf)*16384;                                            \
    char* dB = smem + 32768 + (buf)*16384;                                    \
    _Pragma("unroll") for (int pp = 0; pp < 4; ++pp) {                        \
      int c = pp * 4 + w;                                                     \
      int row = c * 8 + srow;                                                 \
      int loff = c * 1024;                                                    \
      size_t goa = (size_t)(m0 + row) * 512 + kb + sslot * 8;                 \
      size_t gob = (size_t)(n0 + row) * Kg + (k0) + sslot * 8;                \
      __builtin_amdgcn_global_load_lds(                                       \
          (const __attribute__((address_space(1))) void*)(Asrc + goa),        \
          (__attribute__((address_space(3))) void*)(dA + loff), 16, 0, 0);    \
      __builtin_amdgcn_global_load_lds(                                       \
          (const __attribute__((address_space(1))) void*)(Bmat + gob),        \
          (__attribute__((address_space(3))) void*)(dB + loff), 16, 0, 0);    \
    }                                                                         \
  }

  F12_STAGE(0, 0);
  __syncthreads();
  for (int t = 0; t < nt; ++t) {
    if (t + 1 < nt) F12_STAGE((t + 1) & 1, (t + 1) * 64);
    const char* sA = smem + (t & 1) * 16384;
    const char* sB = smem + 32768 + (t & 1) * 16384;
#pragma unroll
    for (int ks = 0; ks < 2; ++ks) {
      bf16x8 av[4], bv[4];
#pragma unroll
      for (int i = 0; i < 4; ++i)
        av[i] = *(const bf16x8*)(sA + (wm * 64 + i * 16 + lr) * 128 +
                                 (((ks * 4 + lk) ^ sx) * 16));
#pragma unroll
      for (int j = 0; j < 4; ++j)
        bv[j] = *(const bf16x8*)(sB + (wn * 64 + j * 16 + lr) * 128 +
                                 (((ks * 4 + lk) ^ sx) * 16));
#pragma unroll
      for (int i = 0; i < 4; ++i)
#pragma unroll
        for (int j = 0; j < 4; ++j)
          acc[i][j] = __builtin_amdgcn_mfma_f32_16x16x32_bf16(av[i], bv[j],
                                                              acc[i][j], 0, 0, 0);
    }
    __syncthreads();
  }
#undef F12_STAGE

  const int mwb = m0 + wm * 64;
  const int nwb = n0 + wn * 64;
  const float* bias = g ? cvec : b1;
#pragma unroll
  for (int j = 0; j < 4; ++j) {
    int nn = nwb + j * 16 + lr;
    float bv = bias[nn];
#pragma unroll
    for (int i = 0; i < 4; ++i) {
#pragma unroll
      for (int r = 0; r < 4; ++r) {
        int m = mwb + i * 16 + lk * 4 + r;
        float v = acc[i][j][r] + bv;
        v = g ? fmaxf(1.f - v, 0.f) : fmaxf(v, 0.f);
        Hout[(size_t)m * 1024 + g * 512 + nn] = f2bf(v);
      }
    }
  }
}

// G3: out = w0*x + w1*relu(Hh @ Wth^T + b_out). K=1024, 128x128, BK=64,
// hi-only, double-buffered 2-phase, LDS 64KB. 512 blocks, XCD swizzle.
__global__ __launch_bounds__(256, 2) void gemm3(
    const u16* __restrict__ Ah, const u16* __restrict__ Bh,
    const float* __restrict__ bias, const float* __restrict__ xorig,
    const float* __restrict__ wadd, float* __restrict__ outp) {
  extern __shared__ char smem[];
  const int tid = threadIdx.x;
  const int l = tid & 63;
  const int w = tid >> 6;
  const int wm = w & 1, wn = w >> 1;
  const int lr = l & 15, lk = l >> 4;
  const int sx = lr & 7;
  const int bid = blockIdx.x;
  const int lin = (bid & 7) * 64 + (bid >> 3);
  const int m0 = (lin >> 2) * 128, n0 = (lin & 3) * 128;
  const int srow = l >> 3;
  const int sslot = (l & 7) ^ srow;

  f32x4 acc[4][4];
#pragma unroll
  for (int i = 0; i < 4; ++i)
#pragma unroll
    for (int j = 0; j < 4; ++j) acc[i][j] = (f32x4){0.f, 0.f, 0.f, 0.f};

#define G3_STAGE(buf, k0)                                                     \
  {                                                                           \
    char* dA = smem + (buf)*16384;                                            \
    char* dB = smem + 32768 + (buf)*16384;                                    \
    _Pragma("unroll") for (int pp = 0; pp < 4; ++pp) {                        \
      int c = pp * 4 + w;                                                     \
      int row = c * 8 + srow;                                                 \
      int loff = c * 1024;                                                    \
      size_t gob = (size_t)(n0 + row) * 1024 + (k0) + sslot * 8;              \
      size_t goa = (size_t)(m0 + row) * 1024 + (k0) + sslot * 8;              \
      __builtin_amdgcn_global_load_lds(                                       \
          (const __attribute__((address_space(1))) void*)(Bh + gob),          \
          (__attribute__((address_space(3))) void*)(dB + loff), 16, 0, 0);    \
      __builtin_amdgcn_global_load_lds(                                       \
          (const __attribute__((address_space(1))) void*)(Ah + goa),          \
          (__attribute__((address_space(3))) void*)(dA + loff), 16, 0, 0);    \
    }                                                                         \
  }

  G3_STAGE(0, 0);
  __syncthreads();
  for (int t = 0; t < 16; ++t) {
    if (t + 1 < 16) G3_STAGE((t + 1) & 1, (t + 1) * 64);
    const char* sA = smem + (t & 1) * 16384;
    const char* sB = smem + 32768 + (t & 1) * 16384;
#pragma unroll
    for (int ks = 0; ks < 2; ++ks) {
      bf16x8 av[4], bv[4];
#pragma unroll
      for (int i = 0; i < 4; ++i)
        av[i] = *(const bf16x8*)(sA + (wm * 64 + i * 16 + lr) * 128 +
                                 (((ks * 4 + lk) ^ sx) * 16));
#pragma unroll
      for (int j = 0; j < 4; ++j)
        bv[j] = *(const bf16x8*)(sB + (wn * 64 + j * 16 + lr) * 128 +
                                 (((ks * 4 + lk) ^ sx) * 16));
#pragma unroll
      for (int i = 0; i < 4; ++i)
#pragma unroll
        for (int j = 0; j < 4; ++j)
          acc[i][j] = __builtin_amdgcn_mfma_f32_16x16x32_bf16(av[i], bv[j],
                                                              acc[i][j], 0, 0, 0);
    }
    __syncthreads();
  }
#undef G3_STAGE

  const int mwb = m0 + wm * 64;
  const int nwb = n0 + wn * 64;
  float w0 = wadd[0], w1 = wadd[1];
#pragma unroll
  for (int j = 0; j < 4; ++j) {
    int n = nwb + j * 16 + lr;
    float bv = bias[n];
#pragma unroll
    for (int i = 0; i < 4; ++i) {
#pragma unroll
      for (int r = 0; r < 4; ++r) {
        int m = mwb + i * 16 + lk * 4 + r;
        float v = fmaxf(acc[i][j][r] + bv, 0.f);
        outp[(size_t)m * 512 + n] = fmaf(w1, v, w0 * xorig[(size_t)m * 512 + n]);
      }
    }
  }
}

// One wave per row of 512. Newton on f(tau)=sum(relu(z-tau))-1. In place.
__global__ __launch_bounds__(256) void sparsemax_kernel(float* __restrict__ out) {
  int row = blockIdx.x * 4 + (threadIdx.x >> 6);
  int lane = threadIdx.x & 63;
  float* rp = out + (size_t)row * 512;
  f4 z0 = *(const f4*)(rp + lane * 8);
  f4 z1 = *(const f4*)(rp + lane * 8 + 4);
  float z[8];
#pragma unroll
  for (int e = 0; e < 4; ++e) {
    z[e] = z0[e];
    z[4 + e] = z1[e];
  }
  float m = z[0];
#pragma unroll
  for (int i = 1; i < 8; ++i) m = fmaxf(m, z[i]);
#pragma unroll
  for (int off = 32; off; off >>= 1) m = fmaxf(m, __shfl_xor(m, off));
  float tau = m - 1.0f;
  for (int it = 0; it < 32; ++it) {
    float s = 0.f, k = 0.f;
#pragma unroll
    for (int i = 0; i < 8; ++i) {
      if (z[i] > tau) {
        s += z[i] - tau;
        k += 1.f;
      }
    }
#pragma unroll
    for (int off = 32; off; off >>= 1) {
      s += __shfl_xor(s, off);
      k += __shfl_xor(k, off);
    }
    if (k < 0.5f) break;
    float tn = tau + (s - 1.f) / k;
    if (tn == tau) break;
    tau = tn;
  }
  float s = 0.f, k = 0.f;
#pragma unroll
  for (int i = 0; i < 8; ++i)
    if (z[i] > tau) {
      s += z[i];
      k += 1.f;
    }
#pragma unroll
  for (int off = 32; off; off >>= 1) {
    s += __shfl_xor(s, off);
    k += __shfl_xor(k, off);
  }
  float tauf = (k >= 0.5f) ? (s - 1.f) / k : (m - 1.f);
  f4 o0, o1;
#pragma unroll
  for (int e = 0; e < 4; ++e) {
    o0[e] = fmaxf(z[e] - tauf, 0.f);
    o1[e] = fmaxf(z[4 + e] - tauf, 0.f);
  }
  *(f4*)(rp + lane * 8) = o0;
  *(f4*)(rp + lane * 8 + 4) = o1;
}

extern "C" void kernel_launch(void* const* d_in, const int* in_sizes, int n_in,
                              void* d_out, int out_size, void* d_ws,
                              size_t ws_size, hipStream_t stream) {
  const float* x = (const float*)d_in[0];
  const float* W1 = (const float*)d_in[1];
  const float* b1 = (const float*)d_in[2];
  const float* centers = (const float*)d_in[3];
  const float* coefs = (const float*)d_in[4];
  const float* gamma = (const float*)d_in[5];
  const float* beta = (const float*)d_in[6];
  const float* mean = (const float*)d_in[7];
  const float* var = (const float*)d_in[8];
  const float* W_out = (const float*)d_in[9];
  const float* b_out = (const float*)d_in[10];
  const float* wadd = (const float*)d_in[11];
  float* out = (float*)d_out;

  // Base layout: 69,212,160 B == round-1-proven ws_size floor.
  char* ws = (char*)d_ws;
  u16* Hh = (u16*)(ws);                      // [16384][1024] bf16 = 32 MB
  u16* Xh = (u16*)(ws + 33554432);           // [16384][512]  bf16 = 16 MB
  u16* Xb = (u16*)(ws + 50331648);           // [16384][512]  bf16 = 16 MB
  char* pool = ws + 67108864;                // 2 MB
  u16* W1th = (u16*)(pool);
  u16* Pth = (u16*)(pool + 1048576);
  float* cvec = (float*)(ws + 69206016);     // 2 KB
  float* scale = (float*)(ws + 69208064);    // 2 KB
  float* shift = (float*)(ws + 69210112);    // 2 KB
  // Xsq lives in d_out (32 MB fp32): dead scratch until G3 fully overwrites
  // it (stream-ordered, deterministic across replays).
  u16* Xsq = (u16*)d_out;
  // Wth: appended at +69,212,160 when ws_size allows (early transpose, no
  // mid-stream dependency); else aliased onto pool (late transpose).
  const bool bigws = (ws_size >= (size_t)70260736);
  u16* Wth = bigws ? (u16*)(ws + 69212160) : (u16*)(pool);

  prep_bn_kernel<<<2, 256, 0, stream>>>(gamma, beta, mean, var, scale, shift);
  prep_params_kernel<<<512, 64, 0, stream>>>(coefs, centers, Pth, cvec);
  transpose_split_kernel<<<dim3(16, 16), dim3(32, 8), 0, stream>>>(W1, W1th,
                                                                   512, 512);
  if (bigws) {
    transpose_split_kernel<<<dim3(16, 32), dim3(32, 8), 0, stream>>>(
        W_out, Wth, 1024, 512);
  }
  conv_x_kernel<<<4096, 256, 0, stream>>>(x, scale, shift, Xh, Xb, Xsq);

  // Merged G1+G2, double-buffered, all-gload_lds.
  gemm_fused12<<<1024, 256, 65536, stream>>>(Xh, Xb, Xsq, W1th, Pth, b1, cvec,
                                             Hh);

  if (!bigws) {
    // pool reuse -> must run after fused12 (stream-ordered).
    transpose_split_kernel<<<dim3(16, 32), dim3(32, 8), 0, stream>>>(
        W_out, Wth, 1024, 512);
  }
  gemm3<<<512, 256, 65536, stream>>>(Hh, Wth, b_out, x, wadd, out);
  sparsemax_kernel<<<4096, 256, 0, stream>>>(out);
}

// Round 11
// 106.263 us; speedup vs baseline: 5.8562x; 1.0134x over previous
//
#include <hip/hip_runtime.h>
#include <math.h>

typedef float f4 __attribute__((ext_vector_type(4)));
typedef float f32x4 __attribute__((ext_vector_type(4)));
typedef __bf16 bf16x8 __attribute__((ext_vector_type(8)));
typedef unsigned short u16;
typedef u16 us8 __attribute__((ext_vector_type(8)));

__device__ __forceinline__ u16 f2bf(float f) {
  unsigned u = __builtin_bit_cast(unsigned, f);
  unsigned r = u + 0x7fffu + ((u >> 16) & 1u);
  return (u16)(r >> 16);
}
__device__ __forceinline__ float bf2f(u16 h) {
  unsigned u = ((unsigned)h) << 16;
  return __builtin_bit_cast(float, u);
}

// scale[d] = rsqrt(var+eps)*gamma ; shift[d] = beta - mean*scale
__global__ __launch_bounds__(256) void prep_bn_kernel(
    const float* __restrict__ gamma, const float* __restrict__ beta,
    const float* __restrict__ mean, const float* __restrict__ var,
    float* __restrict__ scale, float* __restrict__ shift) {
  int d = blockIdx.x * blockDim.x + threadIdx.x;
  if (d < 512) {
    float s = rsqrtf(var[d] + 1e-3f) * gamma[d];
    scale[d] = s;
    shift[d] = beta[d] - mean[d] * s;
  }
}

// Pth[j][k] (bf16, [512][1024]): k<512 -> coefs^2 ; k>=512 -> -2*coefs^2*centers
// cvec[j] = sum_d coefs^2*centers^2  (fp32)
__global__ __launch_bounds__(64) void prep_params_kernel(
    const float* __restrict__ coefs, const float* __restrict__ centers,
    u16* __restrict__ pth, float* __restrict__ cvec) {
  int j = blockIdx.x;
  int l = threadIdx.x;
  int d0 = l * 8;
  f4 c0 = *(const f4*)(coefs + (size_t)j * 512 + d0);
  f4 c1 = *(const f4*)(coefs + (size_t)j * 512 + d0 + 4);
  f4 e0 = *(const f4*)(centers + (size_t)j * 512 + d0);
  f4 e1 = *(const f4*)(centers + (size_t)j * 512 + d0 + 4);
  us8 pa, pb;
  float acc = 0.f;
#pragma unroll
  for (int e = 0; e < 8; ++e) {
    float cf = (e < 4) ? c0[e] : c1[e - 4];
    float ce = (e < 4) ? e0[e] : e1[e - 4];
    float a = cf * cf;
    pa[e] = f2bf(a);
    pb[e] = f2bf(-2.f * a * ce);
    acc = fmaf(a * ce, ce, acc);
  }
  *(us8*)(pth + (size_t)j * 1024 + d0) = pa;
  *(us8*)(pth + (size_t)j * 1024 + 512 + d0) = pb;
#pragma unroll
  for (int off = 32; off; off >>= 1) acc += __shfl_xor(acc, off);
  if (l == 0) cvec[j] = acc;
}

// Transpose [K][N] fp32 -> Th [N][K] bf16 (hi only)
__global__ __launch_bounds__(256) void transpose_split_kernel(
    const float* __restrict__ in, u16* __restrict__ th, int K, int N) {
  __shared__ float t[32][33];
  int lx = threadIdx.x;  // 32
  int ly = threadIdx.y;  // 8
  int n0 = blockIdx.x * 32, k0 = blockIdx.y * 32;
#pragma unroll
  for (int i = 0; i < 4; ++i)
    t[ly + 8 * i][lx] = in[(size_t)(k0 + ly + 8 * i) * N + n0 + lx];
  __syncthreads();
#pragma unroll
  for (int i = 0; i < 4; ++i) {
    float v = t[lx][ly + 8 * i];
    th[(size_t)(n0 + ly + 8 * i) * K + k0 + lx] = f2bf(v);
  }
}

// x [16384][512] fp32 -> Xh = bf16(x), Xb = bf16(xb), Xsq = bf16(xb*xb)
__global__ __launch_bounds__(256) void conv_x_kernel(
    const float* __restrict__ x, const float* __restrict__ scale,
    const float* __restrict__ shift, u16* __restrict__ xh,
    u16* __restrict__ xb, u16* __restrict__ xsq) {
  int gid = blockIdx.x * 256 + threadIdx.x;
  int m = gid >> 6;
  int d0 = (gid & 63) * 8;
  f4 v0 = *(const f4*)(x + (size_t)m * 512 + d0);
  f4 v1 = *(const f4*)(x + (size_t)m * 512 + d0 + 4);
  f4 s0 = *(const f4*)(scale + d0);
  f4 s1 = *(const f4*)(scale + d0 + 4);
  f4 h0 = *(const f4*)(shift + d0);
  f4 h1 = *(const f4*)(shift + d0 + 4);
  us8 oh, ob, oq;
#pragma unroll
  for (int e = 0; e < 8; ++e) {
    float xv = (e < 4) ? v0[e] : v1[e - 4];
    float sc = (e < 4) ? s0[e] : s1[e - 4];
    float sh = (e < 4) ? h0[e] : h1[e - 4];
    oh[e] = f2bf(xv);
    float xbf = fmaf(xv, sc, sh);
    ob[e] = f2bf(xbf);
    oq[e] = f2bf(xbf * xbf);
  }
  *(us8*)(xh + (size_t)m * 512 + d0) = oh;
  *(us8*)(xb + (size_t)m * 512 + d0) = ob;
  *(us8*)(xsq + (size_t)m * 512 + d0) = oq;
}

__device__ __forceinline__ void wait_vm8() {
  asm volatile("s_waitcnt vmcnt(8)" ::: "memory");
}
__device__ __forceinline__ void wait_vm0() {
  asm volatile("s_waitcnt vmcnt(0)" ::: "memory");
}
__device__ __forceinline__ void sbar() { __builtin_amdgcn_s_barrier(); }
__device__ __forceinline__ void sgb0() { __builtin_amdgcn_sched_barrier(0); }

// Merged G1+G2, counted-vmcnt 2-tile-ahead pipeline (T4): raw s_barrier, no
// vmcnt(0) drain in the main loop. 1024 blocks, 128x128, BK=64. LDS 64KB.
// Per STAGE: 8 global_load_lds/thread. Prologue stages tiles 0,1 (16 in
// flight); iter t: vmcnt(8) [t done, t+1 flying]; barrier; MFMA on buf(t&1);
// barrier; stage t+2 into buf(t&1).
__global__ __launch_bounds__(256, 2) void gemm_fused12(
    const u16* __restrict__ Xh, const u16* __restrict__ Xb,
    const u16* __restrict__ Xsq, const u16* __restrict__ W1th,
    const u16* __restrict__ Pth, const float* __restrict__ b1,
    const float* __restrict__ cvec, u16* __restrict__ Hout) {
  extern __shared__ char smem[];
  const int tid = threadIdx.x;
  const int l = tid & 63;
  const int w = tid >> 6;
  const int wm = w & 1, wn = w >> 1;
  const int lr = l & 15, lk = l >> 4;
  const int sx = lr & 7;
  const int bid = blockIdx.x;
  const int L = (bid & 7) * 128 + (bid >> 3);
  const int p = L >> 3;
  const int g = ((L >> 2) & 1) ^ 1;
  const int n = L & 3;
  const int m0 = p * 128, n0 = n * 128;
  const int Kg = g ? 1024 : 512;
  const int nt = g ? 16 : 8;
  const u16* Bmat = g ? Pth : W1th;
  const int srow = l >> 3;
  const int sslot = (l & 7) ^ srow;

  f32x4 acc[4][4];
#pragma unroll
  for (int i = 0; i < 4; ++i)
#pragma unroll
    for (int j = 0; j < 4; ++j) acc[i][j] = (f32x4){0.f, 0.f, 0.f, 0.f};

#define F12_STAGE(buf, k0)                                                    \
  {                                                                           \
    const u16* Asrc = g ? (((k0) < 512) ? Xsq : Xb) : Xh;                     \
    const int kb = (k0)&511;                                                  \
    char* dA = smem + (buf)*16384;                                            \
    char* dB = smem + 32768 + (buf)*16384;                                    \
    _Pragma("unroll") for (int pp = 0; pp < 4; ++pp) {                        \
      int c = pp * 4 + w;                                                     \
      int row = c * 8 + srow;                                                 \
      int loff = c * 1024;                                                    \
      size_t goa = (size_t)(m0 + row) * 512 + kb + sslot * 8;                 \
      size_t gob = (size_t)(n0 + row) * Kg + (k0) + sslot * 8;                \
      __builtin_amdgcn_global_load_lds(                                       \
          (const __attribute__((address_space(1))) void*)(Asrc + goa),        \
          (__attribute__((address_space(3))) void*)(dA + loff), 16, 0, 0);    \
      __builtin_amdgcn_global_load_lds(                                       \
          (const __attribute__((address_space(1))) void*)(Bmat + gob),        \
          (__attribute__((address_space(3))) void*)(dB + loff), 16, 0, 0);    \
    }                                                                         \
  }

  F12_STAGE(0, 0);
  F12_STAGE(1, 64);
  for (int t = 0; t < nt; ++t) {
    if (t + 1 < nt) {
      wait_vm8();
    } else {
      wait_vm0();
    }
    sgb0();
    sbar();
    sgb0();
    const char* sA = smem + (t & 1) * 16384;
    const char* sB = smem + 32768 + (t & 1) * 16384;
#pragma unroll
    for (int ks = 0; ks < 2; ++ks) {
      bf16x8 av[4], bv[4];
#pragma unroll
      for (int i = 0; i < 4; ++i)
        av[i] = *(const bf16x8*)(sA + (wm * 64 + i * 16 + lr) * 128 +
                                 (((ks * 4 + lk) ^ sx) * 16));
#pragma unroll
      for (int j = 0; j < 4; ++j)
        bv[j] = *(const bf16x8*)(sB + (wn * 64 + j * 16 + lr) * 128 +
                                 (((ks * 4 + lk) ^ sx) * 16));
#pragma unroll
      for (int i = 0; i < 4; ++i)
#pragma unroll
        for (int j = 0; j < 4; ++j)
          acc[i][j] = __builtin_amdgcn_mfma_f32_16x16x32_bf16(av[i], bv[j],
                                                              acc[i][j], 0, 0, 0);
    }
    sgb0();
    sbar();
    sgb0();
    if (t + 2 < nt) F12_STAGE(t & 1, (t + 2) * 64);
  }
#undef F12_STAGE

  const int mwb = m0 + wm * 64;
  const int nwb = n0 + wn * 64;
  const float* bias = g ? cvec : b1;
#pragma unroll
  for (int j = 0; j < 4; ++j) {
    int nn = nwb + j * 16 + lr;
    float bv = bias[nn];
#pragma unroll
    for (int i = 0; i < 4; ++i) {
#pragma unroll
      for (int r = 0; r < 4; ++r) {
        int m = mwb + i * 16 + lk * 4 + r;
        float v = acc[i][j][r] + bv;
        v = g ? fmaxf(1.f - v, 0.f) : fmaxf(v, 0.f);
        Hout[(size_t)m * 1024 + g * 512 + nn] = f2bf(v);
      }
    }
  }
}

// G3: out = w0*x + w1*relu(Hh @ Wth^T + b_out). K=1024, counted-vmcnt 2-ahead
// pipeline, LDS 64KB. 512 blocks, XCD swizzle.
__global__ __launch_bounds__(256, 2) void gemm3(
    const u16* __restrict__ Ah, const u16* __restrict__ Bh,
    const float* __restrict__ bias, const float* __restrict__ xorig,
    const float* __restrict__ wadd, float* __restrict__ outp) {
  extern __shared__ char smem[];
  const int tid = threadIdx.x;
  const int l = tid & 63;
  const int w = tid >> 6;
  const int wm = w & 1, wn = w >> 1;
  const int lr = l & 15, lk = l >> 4;
  const int sx = lr & 7;
  const int bid = blockIdx.x;
  const int lin = (bid & 7) * 64 + (bid >> 3);
  const int m0 = (lin >> 2) * 128, n0 = (lin & 3) * 128;
  const int srow = l >> 3;
  const int sslot = (l & 7) ^ srow;

  f32x4 acc[4][4];
#pragma unroll
  for (int i = 0; i < 4; ++i)
#pragma unroll
    for (int j = 0; j < 4; ++j) acc[i][j] = (f32x4){0.f, 0.f, 0.f, 0.f};

#define G3_STAGE(buf, k0)                                                     \
  {                                                                           \
    char* dA = smem + (buf)*16384;                                            \
    char* dB = smem + 32768 + (buf)*16384;                                    \
    _Pragma("unroll") for (int pp = 0; pp < 4; ++pp) {                        \
      int c = pp * 4 + w;                                                     \
      int row = c * 8 + srow;                                                 \
      int loff = c * 1024;                                                    \
      size_t gob = (size_t)(n0 + row) * 1024 + (k0) + sslot * 8;              \
      size_t goa = (size_t)(m0 + row) * 1024 + (k0) + sslot * 8;              \
      __builtin_amdgcn_global_load_lds(                                       \
          (const __attribute__((address_space(1))) void*)(Bh + gob),          \
          (__attribute__((address_space(3))) void*)(dB + loff), 16, 0, 0);    \
      __builtin_amdgcn_global_load_lds(                                       \
          (const __attribute__((address_space(1))) void*)(Ah + goa),          \
          (__attribute__((address_space(3))) void*)(dA + loff), 16, 0, 0);    \
    }                                                                         \
  }

  G3_STAGE(0, 0);
  G3_STAGE(1, 64);
  for (int t = 0; t < 16; ++t) {
    if (t + 1 < 16) {
      wait_vm8();
    } else {
      wait_vm0();
    }
    sgb0();
    sbar();
    sgb0();
    const char* sA = smem + (t & 1) * 16384;
    const char* sB = smem + 32768 + (t & 1) * 16384;
#pragma unroll
    for (int ks = 0; ks < 2; ++ks) {
      bf16x8 av[4], bv[4];
#pragma unroll
      for (int i = 0; i < 4; ++i)
        av[i] = *(const bf16x8*)(sA + (wm * 64 + i * 16 + lr) * 128 +
                                 (((ks * 4 + lk) ^ sx) * 16));
#pragma unroll
      for (int j = 0; j < 4; ++j)
        bv[j] = *(const bf16x8*)(sB + (wn * 64 + j * 16 + lr) * 128 +
                                 (((ks * 4 + lk) ^ sx) * 16));
#pragma unroll
      for (int i = 0; i < 4; ++i)
#pragma unroll
        for (int j = 0; j < 4; ++j)
          acc[i][j] = __builtin_amdgcn_mfma_f32_16x16x32_bf16(av[i], bv[j],
                                                              acc[i][j], 0, 0, 0);
    }
    sgb0();
    sbar();
    sgb0();
    if (t + 2 < 16) G3_STAGE(t & 1, (t + 2) * 64);
  }
#undef G3_STAGE

  const int mwb = m0 + wm * 64;
  const int nwb = n0 + wn * 64;
  float w0 = wadd[0], w1 = wadd[1];
#pragma unroll
  for (int j = 0; j < 4; ++j) {
    int n = nwb + j * 16 + lr;
    float bv = bias[n];
#pragma unroll
    for (int i = 0; i < 4; ++i) {
#pragma unroll
      for (int r = 0; r < 4; ++r) {
        int m = mwb + i * 16 + lk * 4 + r;
        float v = fmaxf(acc[i][j][r] + bv, 0.f);
        outp[(size_t)m * 512 + n] = fmaf(w1, v, w0 * xorig[(size_t)m * 512 + n]);
      }
    }
  }
}

// One wave per row of 512. XCD-aligned work swizzle: rows are read on the
// XCD whose L2 holds them from gemm3's write (G3 panel p -> XCD p/16).
__global__ __launch_bounds__(256) void sparsemax_kernel(float* __restrict__ out) {
  int wrk = (blockIdx.x & 7) * 512 + (blockIdx.x >> 3);
  int row = wrk * 4 + (threadIdx.x >> 6);
  int lane = threadIdx.x & 63;
  float* rp = out + (size_t)row * 512;
  f4 z0 = *(const f4*)(rp + lane * 8);
  f4 z1 = *(const f4*)(rp + lane * 8 + 4);
  float z[8];
#pragma unroll
  for (int e = 0; e < 4; ++e) {
    z[e] = z0[e];
    z[4 + e] = z1[e];
  }
  float m = z[0];
#pragma unroll
  for (int i = 1; i < 8; ++i) m = fmaxf(m, z[i]);
#pragma unroll
  for (int off = 32; off; off >>= 1) m = fmaxf(m, __shfl_xor(m, off));
  float tau = m - 1.0f;
  for (int it = 0; it < 32; ++it) {
    float s = 0.f, k = 0.f;
#pragma unroll
    for (int i = 0; i < 8; ++i) {
      if (z[i] > tau) {
        s += z[i] - tau;
        k += 1.f;
      }
    }
#pragma unroll
    for (int off = 32; off; off >>= 1) {
      s += __shfl_xor(s, off);
      k += __shfl_xor(k, off);
    }
    if (k < 0.5f) break;
    float tn = tau + (s - 1.f) / k;
    if (tn == tau) break;
    tau = tn;
  }
  float s = 0.f, k = 0.f;
#pragma unroll
  for (int i = 0; i < 8; ++i)
    if (z[i] > tau) {
      s += z[i];
      k += 1.f;
    }
#pragma unroll
  for (int off = 32; off; off >>= 1) {
    s += __shfl_xor(s, off);
    k += __shfl_xor(k, off);
  }
  float tauf = (k >= 0.5f) ? (s - 1.f) / k : (m - 1.f);
  f4 o0, o1;
#pragma unroll
  for (int e = 0; e < 4; ++e) {
    o0[e] = fmaxf(z[e] - tauf, 0.f);
    o1[e] = fmaxf(z[4 + e] - tauf, 0.f);
  }
  *(f4*)(rp + lane * 8) = o0;
  *(f4*)(rp + lane * 8 + 4) = o1;
}

extern "C" void kernel_launch(void* const* d_in, const int* in_sizes, int n_in,
                              void* d_out, int out_size, void* d_ws,
                              size_t ws_size, hipStream_t stream) {
  const float* x = (const float*)d_in[0];
  const float* W1 = (const float*)d_in[1];
  const float* b1 = (const float*)d_in[2];
  const float* centers = (const float*)d_in[3];
  const float* coefs = (const float*)d_in[4];
  const float* gamma = (const float*)d_in[5];
  const float* beta = (const float*)d_in[6];
  const float* mean = (const float*)d_in[7];
  const float* var = (const float*)d_in[8];
  const float* W_out = (const float*)d_in[9];
  const float* b_out = (const float*)d_in[10];
  const float* wadd = (const float*)d_in[11];
  float* out = (float*)d_out;

  // Base layout: 69,212,160 B == round-1-proven ws_size floor.
  char* ws = (char*)d_ws;
  u16* Hh = (u16*)(ws);                      // [16384][1024] bf16 = 32 MB
  u16* Xh = (u16*)(ws + 33554432);           // [16384][512]  bf16 = 16 MB
  u16* Xb = (u16*)(ws + 50331648);           // [16384][512]  bf16 = 16 MB
  char* pool = ws + 67108864;                // 2 MB
  u16* W1th = (u16*)(pool);
  u16* Pth = (u16*)(pool + 1048576);
  float* cvec = (float*)(ws + 69206016);     // 2 KB
  float* scale = (float*)(ws + 69208064);    // 2 KB
  float* shift = (float*)(ws + 69210112);    // 2 KB
  // Xsq lives in d_out (32 MB fp32): dead scratch until G3 overwrites it.
  u16* Xsq = (u16*)d_out;
  const bool bigws = (ws_size >= (size_t)70260736);
  u16* Wth = bigws ? (u16*)(ws + 69212160) : (u16*)(pool);

  prep_bn_kernel<<<2, 256, 0, stream>>>(gamma, beta, mean, var, scale, shift);
  prep_params_kernel<<<512, 64, 0, stream>>>(coefs, centers, Pth, cvec);
  transpose_split_kernel<<<dim3(16, 16), dim3(32, 8), 0, stream>>>(W1, W1th,
                                                                   512, 512);
  if (bigws) {
    transpose_split_kernel<<<dim3(16, 32), dim3(32, 8), 0, stream>>>(
        W_out, Wth, 1024, 512);
  }
  conv_x_kernel<<<4096, 256, 0, stream>>>(x, scale, shift, Xh, Xb, Xsq);

  gemm_fused12<<<1024, 256, 65536, stream>>>(Xh, Xb, Xsq, W1th, Pth, b1, cvec,
                                             Hh);

  if (!bigws) {
    transpose_split_kernel<<<dim3(16, 32), dim3(32, 8), 0, stream>>>(
        W_out, Wth, 1024, 512);
  }
  gemm3<<<512, 256, 65536, stream>>>(Hh, Wth, b_out, x, wadd, out);
  sparsemax_kernel<<<4096, 256, 0, stream>>>(out);
}